// Round 3
// baseline (8076.313 us; speedup 1.0000x reference)
//
#include <hip/hip_runtime.h>

static __device__ __forceinline__ float frelu(float v) { return v > 0.f ? v : 0.f; }

// ---------- encoder conv1: 4x4 s2 p1, 3->64, bias+relu, 256^2 -> 128^2 ----------
__global__ __launch_bounds__(256) void k_ew1(const float* __restrict__ x,
    const float* __restrict__ w, const float* __restrict__ bias, float* __restrict__ out)
{
    const int t = threadIdx.x;
    const int tile = blockIdx.x;          // 64 tiles (8x8) of 16x16 over 128x128
    const int b = blockIdx.y;
    const int oy0 = (tile >> 3) << 4, ox0 = (tile & 7) << 4;
    const int tx = t & 15, ty = t >> 4;
    const int iy0 = 2 * oy0 - 1, ix0 = 2 * ox0 - 1;

    __shared__ float s_in[3 * 34 * 35];
    for (int i = t; i < 3 * 1156; i += 256) {
        int ci = i / 1156, rem = i % 1156, r = rem / 34, c = rem % 34;
        int gy = iy0 + r, gx = ix0 + c;
        float v = 0.f;
        if ((unsigned)gy < 256u && (unsigned)gx < 256u)
            v = x[((b * 3 + ci) * 256 + gy) * 256 + gx];
        s_in[(ci * 34 + r) * 35 + c] = v;
    }
    __syncthreads();

    float acc[64];
#pragma unroll
    for (int i = 0; i < 64; ++i) acc[i] = 0.f;
#pragma unroll
    for (int ci = 0; ci < 3; ++ci) {
        float v[16];
#pragma unroll
        for (int ky = 0; ky < 4; ++ky)
#pragma unroll
            for (int kx = 0; kx < 4; ++kx)
                v[ky * 4 + kx] = s_in[(ci * 34 + 2 * ty + ky) * 35 + 2 * tx + kx];
#pragma unroll
        for (int co = 0; co < 64; ++co)
#pragma unroll
            for (int k = 0; k < 16; ++k)
                acc[co] += v[k] * w[(co * 3 + ci) * 16 + k];
    }
#pragma unroll
    for (int co = 0; co < 64; ++co)
        out[((b * 64 + co) * 128 + oy0 + ty) * 128 + ox0 + tx] = frelu(acc[co] + bias[co]);
}

// ---------- encoder conv2: 4x4 s2 p1, 64->128, parity-split LDS, 16co/thread ----
__global__ __launch_bounds__(256) void k_ew2(const float* __restrict__ in,
    const float* __restrict__ w, const float* __restrict__ bias, float* __restrict__ out)
{
    const int t = threadIdx.x;
    const int tile = blockIdx.x;          // 16 tiles (4x4) of 16x16 over 64x64
    const int bcg = blockIdx.y;           // b*8 + cg   (16 co each)
    const int b = bcg >> 3, cg = bcg & 7;
    const int oy0 = (tile >> 2) << 4, ox0 = (tile & 3) << 4;
    const int tx = t & 15, ty = t >> 4;
    const int iy0 = 2 * oy0 - 1, ix0 = 2 * ox0 - 1;

    // parity-split: [ci4][py2][px2][17][18]; input (r,c) -> plane(r&1,c&1) at (r>>1,c>>1)
    __shared__ float s_in[4 * 4 * 17 * 18];

    constexpr int NS = 19;                // ceil(4*34*34 / 256)
    int goff[NS], loff[NS];
#pragma unroll
    for (int k = 0; k < NS; ++k) {
        int idx = t + (k << 8);
        if (idx < 4624) {
            int ci = idx / 1156, rem = idx % 1156, r = rem / 34, c = rem % 34;
            loff[k] = ((ci * 4 + (r & 1) * 2 + (c & 1)) * 17 + (r >> 1)) * 18 + (c >> 1);
            int gy = iy0 + r, gx = ix0 + c;
            goff[k] = ((unsigned)gy < 128u && (unsigned)gx < 128u)
                      ? ((b * 64 + ci) * 128 + gy) * 128 + gx : -1;
        } else { loff[k] = -1; goff[k] = -1; }
    }

    float acc[16];
#pragma unroll
    for (int i = 0; i < 16; ++i) acc[i] = 0.f;
    float pre[NS];
#pragma unroll
    for (int k = 0; k < NS; ++k) pre[k] = (goff[k] >= 0) ? in[goff[k]] : 0.f;
#pragma unroll
    for (int k = 0; k < NS; ++k) if (loff[k] >= 0) s_in[loff[k]] = pre[k];
    __syncthreads();

#pragma unroll 1
    for (int cc = 0; cc < 16; ++cc) {
        if (cc < 15) {
            const int coff = (cc + 1) * 4 * 16384;
#pragma unroll
            for (int k = 0; k < NS; ++k)
                pre[k] = (goff[k] >= 0) ? in[goff[k] + coff] : 0.f;
        }
#pragma unroll
        for (int ci = 0; ci < 4; ++ci) {
            float v[16];
#pragma unroll
            for (int ky = 0; ky < 4; ++ky)
#pragma unroll
                for (int kx = 0; kx < 4; ++kx)
                    v[ky * 4 + kx] = s_in[((ci * 4 + (ky & 1) * 2 + (kx & 1)) * 17
                                           + ty + (ky >> 1)) * 18 + tx + (kx >> 1)];
#pragma unroll
            for (int co = 0; co < 16; ++co)
#pragma unroll
                for (int k = 0; k < 16; ++k)
                    acc[co] += v[k] * w[((cg * 16 + co) * 64 + cc * 4 + ci) * 16 + k];
        }
        __syncthreads();
        if (cc < 15) {
#pragma unroll
            for (int k = 0; k < NS; ++k) if (loff[k] >= 0) s_in[loff[k]] = pre[k];
            __syncthreads();
        }
    }
#pragma unroll
    for (int co = 0; co < 16; ++co) {
        int oc = cg * 16 + co;
        out[((b * 128 + oc) * 64 + oy0 + ty) * 64 + ox0 + tx] = frelu(acc[co] + bias[oc]);
    }
}

// ---------- generic 3x3 s1 p1 conv at 64x64, reg-prefetch double buffer ---------
template<int CIN, int COUT, int COT, bool RELU, bool HASBIAS>
__global__ __launch_bounds__(256) void k_conv3(const float* __restrict__ in,
    const float* __restrict__ w, const float* __restrict__ bias, float* __restrict__ out)
{
    const int t = threadIdx.x;
    const int tile = blockIdx.x;          // 16 tiles (4x4) of 16x16
    constexpr int NCG = COUT / COT;
    const int bcg = blockIdx.y;
    const int b = bcg / NCG, cg = bcg % NCG;
    const int oy0 = (tile >> 2) << 4, ox0 = (tile & 3) << 4;
    const int tx = t & 15, ty = t >> 4;
    const int iy0 = oy0 - 1, ix0 = ox0 - 1;
    constexpr int NC = CIN / 8;

    __shared__ float s_in[8 * 18 * 19];
    constexpr int NS = 11;                // ceil(8*18*18 / 256)
    int goff[NS], loff[NS];
#pragma unroll
    for (int k = 0; k < NS; ++k) {
        int idx = t + (k << 8);
        if (idx < 2592) {
            int ci = idx / 324, rem = idx % 324, r = rem / 18, c = rem % 18;
            loff[k] = (ci * 18 + r) * 19 + c;
            int gy = iy0 + r, gx = ix0 + c;
            goff[k] = ((unsigned)gy < 64u && (unsigned)gx < 64u)
                      ? ((b * CIN + ci) * 64 + gy) * 64 + gx : -1;
        } else { loff[k] = -1; goff[k] = -1; }
    }

    float acc[COT];
#pragma unroll
    for (int i = 0; i < COT; ++i) acc[i] = 0.f;
    float pre[NS];
#pragma unroll
    for (int k = 0; k < NS; ++k) pre[k] = (goff[k] >= 0) ? in[goff[k]] : 0.f;
#pragma unroll
    for (int k = 0; k < NS; ++k) if (loff[k] >= 0) s_in[loff[k]] = pre[k];
    __syncthreads();

#pragma unroll 1
    for (int cc = 0; cc < NC; ++cc) {
        if (cc < NC - 1) {
            const int coff = (cc + 1) * 8 * 4096;
#pragma unroll
            for (int k = 0; k < NS; ++k)
                pre[k] = (goff[k] >= 0) ? in[goff[k] + coff] : 0.f;
        }
#pragma unroll
        for (int ci = 0; ci < 8; ++ci) {
            float v[9];
#pragma unroll
            for (int ky = 0; ky < 3; ++ky)
#pragma unroll
                for (int kx = 0; kx < 3; ++kx)
                    v[ky * 3 + kx] = s_in[(ci * 18 + ty + ky) * 19 + tx + kx];
#pragma unroll
            for (int co = 0; co < COT; ++co)
#pragma unroll
                for (int k = 0; k < 9; ++k)
                    acc[co] += v[k] * w[((cg * COT + co) * CIN + cc * 8 + ci) * 9 + k];
        }
        __syncthreads();
        if (cc < NC - 1) {
#pragma unroll
            for (int k = 0; k < NS; ++k) if (loff[k] >= 0) s_in[loff[k]] = pre[k];
            __syncthreads();
        }
    }
#pragma unroll
    for (int co = 0; co < COT; ++co) {
        int oc = cg * COT + co;
        float vv = acc[co];
        if (HASBIAS) vv += bias[oc];
        if (RELU) vv = frelu(vv);
        out[((b * COUT + oc) * 64 + oy0 + ty) * 64 + ox0 + tx] = vv;
    }
}

// ---------- residual 1x1: x += relu(conv1x1(t)), 32->128 ------------------------
__global__ __launch_bounds__(256) void k_res1x1(const float* __restrict__ tin,
    const float* __restrict__ w, float* __restrict__ xbuf)
{
    int gid = blockIdx.x * 256 + threadIdx.x;   // 16 * 8 * 4096
    int px = gid & 4095;
    int cg = (gid >> 12) & 7;
    int b = gid >> 15;
    float acc[16];
#pragma unroll
    for (int i = 0; i < 16; ++i) acc[i] = 0.f;
#pragma unroll
    for (int ci = 0; ci < 32; ++ci) {
        float v = tin[(b * 32 + ci) * 4096 + px];
#pragma unroll
        for (int co = 0; co < 16; ++co)
            acc[co] += v * w[(cg * 16 + co) * 32 + ci];
    }
#pragma unroll
    for (int co = 0; co < 16; ++co) {
        int o = (b * 128 + cg * 16 + co) * 4096 + px;
        xbuf[o] = xbuf[o] + frelu(acc[co]);
    }
}

// ---------- VQ pass 1: direct (z-e)^2, round-1 exact semantics, 4 e-slices ------
__global__ __launch_bounds__(256) void k_vq1(const float* __restrict__ z,
    const float* __restrict__ emb, float* __restrict__ distb, int* __restrict__ idxb)
{
    const int gid = blockIdx.x * 256 + threadIdx.x;   // 262144
    const int px = gid & 65535, slice = gid >> 16;
    const int b = px >> 12, h = (px >> 6) & 63, wq = px & 63;
    float zr[64];
#pragma unroll
    for (int d = 0; d < 64; ++d)
        zr[d] = z[((b * 64 + d) * 64 + h) * 64 + wq];

    float best = 3.4e38f; int bi = 0;
    const int e0 = slice * 128;
#pragma unroll 1
    for (int e = 0; e < 128; ++e) {
        const float* er = emb + (e0 + e) * 64;        // block-uniform -> s_load
        float dist = 0.f;
#pragma unroll
        for (int d = 0; d < 64; ++d) {
            float df = zr[d] - er[d];
            dist += df * df;                           // single chain, ascending d
        }
        if (dist < best) { best = dist; bi = e0 + e; } // strict < -> first min
    }
    distb[gid] = best;
    idxb[gid] = bi;
}

// ---------- VQ pass 2: merge slices (ascending -> first-min tiebreak), loss part -
__global__ __launch_bounds__(256) void k_vq2(const float* __restrict__ distb,
    const int* __restrict__ idxb, int* __restrict__ idx, float* __restrict__ part)
{
    const int t = threadIdx.x;
    const int px = blockIdx.x * 256 + t;
    float best = distb[px]; int bi = idxb[px];
#pragma unroll
    for (int s2 = 1; s2 < 4; ++s2) {
        float d = distb[s2 * 65536 + px];
        int i2 = idxb[s2 * 65536 + px];
        if (d < best) { best = d; bi = i2; }
    }
    idx[px] = bi;
    float s = best;
#pragma unroll
    for (int off = 32; off > 0; off >>= 1) s += __shfl_down(s, off, 64);
    __shared__ float sw[4];
    if ((t & 63) == 0) sw[t >> 6] = s;
    __syncthreads();
    if (t == 0) part[blockIdx.x] = sw[0] + sw[1] + sw[2] + sw[3];
}

// ---------- build quantized NCHW via LDS transpose ------------------------------
__global__ __launch_bounds__(256) void k_qbuild(const int* __restrict__ idx,
    const float* __restrict__ emb, float* __restrict__ q)
{
    const int t = threadIdx.x;
    const int bh = blockIdx.x;            // b*64 + h
    const int b = bh >> 6, h = bh & 63;
    __shared__ int s_idx[64];
    __shared__ float s_e[64 * 65];
    if (t < 64) s_idx[t] = idx[(b << 12) | (h << 6) | t];
    __syncthreads();
#pragma unroll
    for (int k = 0; k < 16; ++k) {
        int i = t + (k << 8);
        int wq = i >> 6, d = i & 63;
        s_e[wq * 65 + d] = emb[s_idx[wq] * 64 + d];   // coalesced emb rows
    }
    __syncthreads();
#pragma unroll
    for (int k = 0; k < 16; ++k) {
        int i = t + (k << 8);
        int d = i >> 6, wq = i & 63;
        q[((b * 64 + d) * 64 + h) * 64 + wq] = s_e[wq * 65 + d];
    }
}

__global__ __launch_bounds__(256) void k_loss(const float* __restrict__ part,
    float* __restrict__ out)
{
    int t = threadIdx.x;
    float s = part[t];
#pragma unroll
    for (int off = 32; off > 0; off >>= 1) s += __shfl_down(s, off, 64);
    __shared__ float sw[4];
    if ((t & 63) == 0) sw[t >> 6] = s;
    __syncthreads();
    if (t == 0) out[3145728] = 1.25f * (sw[0] + sw[1] + sw[2] + sw[3]) / 4194304.0f;
}

// ---------- ConvTranspose2d k4 s2 p1 + relu; w layout (CIN,COUT,4,4) ------------
template<int CIN, int COUT, int COT, int OW>
__global__ __launch_bounds__(256) void k_convT(const float* __restrict__ in,
    const float* __restrict__ w, const float* __restrict__ bias, float* __restrict__ out)
{
    constexpr int IW = OW / 2;
    constexpr int TPR = OW / 32;
    const int t = threadIdx.x;
    const int tile = blockIdx.x;              // TPR^2 tiles of 32x32 out
    constexpr int NCG = COUT / COT;
    const int bcg = blockIdx.y;
    const int b = bcg / NCG, cg = bcg % NCG;
    const int oy0 = (tile / TPR) * 32, ox0 = (tile % TPR) * 32;
    const int tx = t & 15, ty = t >> 4;       // thread owns 2x2 out px
    const int iy0 = oy0 / 2 - 1, ix0 = ox0 / 2 - 1;
    constexpr int NC = CIN / 8;

    __shared__ float s_in[8 * 18 * 19];
    constexpr int NS = 11;
    int goff[NS], loff[NS];
#pragma unroll
    for (int k = 0; k < NS; ++k) {
        int idx = t + (k << 8);
        if (idx < 2592) {
            int ci = idx / 324, rem = idx % 324, r = rem / 18, c = rem % 18;
            loff[k] = (ci * 18 + r) * 19 + c;
            int gy = iy0 + r, gx = ix0 + c;
            goff[k] = ((unsigned)gy < (unsigned)IW && (unsigned)gx < (unsigned)IW)
                      ? ((b * CIN + ci) * IW + gy) * IW + gx : -1;
        } else { loff[k] = -1; goff[k] = -1; }
    }

    float acc[4][COT];
#pragma unroll
    for (int a = 0; a < 4; ++a)
#pragma unroll
        for (int c = 0; c < COT; ++c) acc[a][c] = 0.f;
    float pre[NS];
#pragma unroll
    for (int k = 0; k < NS; ++k) pre[k] = (goff[k] >= 0) ? in[goff[k]] : 0.f;
#pragma unroll
    for (int k = 0; k < NS; ++k) if (loff[k] >= 0) s_in[loff[k]] = pre[k];
    __syncthreads();

#pragma unroll 1
    for (int cc = 0; cc < NC; ++cc) {
        if (cc < NC - 1) {
            const int coff = (cc + 1) * 8 * IW * IW;
#pragma unroll
            for (int k = 0; k < NS; ++k)
                pre[k] = (goff[k] >= 0) ? in[goff[k] + coff] : 0.f;
        }
#pragma unroll
        for (int ci = 0; ci < 8; ++ci) {
            float rr[3][3];
#pragma unroll
            for (int dy = 0; dy < 3; ++dy)
#pragma unroll
                for (int dx = 0; dx < 3; ++dx)
                    rr[dy][dx] = s_in[(ci * 18 + ty + dy) * 19 + tx + dx];
#pragma unroll
            for (int co = 0; co < COT; ++co)
#pragma unroll
                for (int ky = 0; ky < 4; ++ky) {
                    const int py = 1 - (ky & 1);
                    const int dy = (ky == 0) ? 2 : (ky == 3) ? 0 : 1;
#pragma unroll
                    for (int kx = 0; kx < 4; ++kx) {
                        const int pxr = 1 - (kx & 1);
                        const int dx = (kx == 0) ? 2 : (kx == 3) ? 0 : 1;
                        acc[py * 2 + pxr][co] += rr[dy][dx]
                            * w[((cc * 8 + ci) * COUT + cg * COT + co) * 16 + ky * 4 + kx];
                    }
                }
        }
        __syncthreads();
        if (cc < NC - 1) {
#pragma unroll
            for (int k = 0; k < NS; ++k) if (loff[k] >= 0) s_in[loff[k]] = pre[k];
            __syncthreads();
        }
    }
    const int ye = oy0 + 2 * ty, xe = ox0 + 2 * tx;
#pragma unroll
    for (int py = 0; py < 2; ++py)
#pragma unroll
        for (int pxr = 0; pxr < 2; ++pxr)
#pragma unroll
            for (int co = 0; co < COT; ++co) {
                int oc = cg * COT + co;
                out[((b * COUT + oc) * OW + ye + py) * OW + xe + pxr] =
                    frelu(acc[py * 2 + pxr][co] + bias[oc]);
            }
}

extern "C" void kernel_launch(void* const* d_in, const int* in_sizes, int n_in,
                              void* d_out, int out_size, void* d_ws, size_t ws_size,
                              hipStream_t stream)
{
    (void)in_sizes; (void)n_in; (void)out_size; (void)ws_size;
    const float* x    = (const float*)d_in[0];
    const float* emb  = (const float*)d_in[1];
    const float* ew1  = (const float*)d_in[2];
    const float* eb1  = (const float*)d_in[3];
    const float* ew2  = (const float*)d_in[4];
    const float* eb2  = (const float*)d_in[5];
    const float* er1a = (const float*)d_in[6];
    const float* er1b = (const float*)d_in[7];
    const float* er2a = (const float*)d_in[8];
    const float* er2b = (const float*)d_in[9];
    const float* ew3w = (const float*)d_in[10];
    const float* eb3  = (const float*)d_in[11];
    const float* dw1  = (const float*)d_in[12];
    const float* db1  = (const float*)d_in[13];
    const float* dr1a = (const float*)d_in[14];
    const float* dr1b = (const float*)d_in[15];
    const float* dr2a = (const float*)d_in[16];
    const float* dr2b = (const float*)d_in[17];
    const float* dtw1 = (const float*)d_in[18];
    const float* dtb1 = (const float*)d_in[19];
    const float* dtw2 = (const float*)d_in[20];
    const float* dtb2 = (const float*)d_in[21];
    float* out = (float*)d_out;
    float* ws  = (float*)d_ws;

    float* A    = ws;                          // [16,64,128,128] h1; later convT1 out
    float* Bf   = ws + 16777216;               // [16,128,64,64]
    float* T    = ws;                          // [16,32,64,64]   (h1 dead after ew2)
    float* Z    = ws + 2097152;                // [16,64,64,64]
    float* Q    = ws + 6291456;                // [16,64,64,64]
    int*   IDX  = (int*)(ws + 10485760);       // 65536
    float* PART = ws + 10551296;               // 256
    float* DISTB= ws + 10552064;               // 4*65536
    int*   IDXB = (int*)(ws + 10814208);       // 4*65536

    k_ew1<<<dim3(64, 16), 256, 0, stream>>>(x, ew1, eb1, A);
    k_ew2<<<dim3(16, 128), 256, 0, stream>>>(A, ew2, eb2, Bf);
    k_conv3<128, 32, 8, true, false><<<dim3(16, 64), 256, 0, stream>>>(Bf, er1a, nullptr, T);
    k_res1x1<<<2048, 256, 0, stream>>>(T, er1b, Bf);
    k_conv3<128, 32, 8, true, false><<<dim3(16, 64), 256, 0, stream>>>(Bf, er2a, nullptr, T);
    k_res1x1<<<2048, 256, 0, stream>>>(T, er2b, Bf);
    k_conv3<128, 64, 16, false, true><<<dim3(16, 64), 256, 0, stream>>>(Bf, ew3w, eb3, Z);
    k_vq1<<<1024, 256, 0, stream>>>(Z, emb, DISTB, IDXB);
    k_vq2<<<256, 256, 0, stream>>>(DISTB, IDXB, IDX, PART);
    k_loss<<<1, 256, 0, stream>>>(PART, out);
    k_qbuild<<<1024, 256, 0, stream>>>(IDX, emb, Q);
    k_conv3<64, 128, 16, false, true><<<dim3(16, 128), 256, 0, stream>>>(Q, dw1, db1, Bf);
    k_conv3<128, 32, 8, true, false><<<dim3(16, 64), 256, 0, stream>>>(Bf, dr1a, nullptr, T);
    k_res1x1<<<2048, 256, 0, stream>>>(T, dr1b, Bf);
    k_conv3<128, 32, 8, true, false><<<dim3(16, 64), 256, 0, stream>>>(Bf, dr2a, nullptr, T);
    k_res1x1<<<2048, 256, 0, stream>>>(T, dr2b, Bf);
    k_convT<128, 64, 16, 128><<<dim3(16, 64), 256, 0, stream>>>(Bf, dtw1, dtb1, A);
    k_convT<64, 3, 3, 256><<<dim3(64, 16), 256, 0, stream>>>(A, dtw2, dtb2, out);
}

// Round 4
// 6879.218 us; speedup vs baseline: 1.1740x; 1.1740x over previous
//
#include <hip/hip_runtime.h>

static __device__ __forceinline__ float frelu(float v) { return v > 0.f ? v : 0.f; }

// ---------- encoder conv1: 4x4 s2 p1, 3->64, bias+relu, 256^2 -> 128^2 ----------
__global__ __launch_bounds__(256) void k_ew1(const float* __restrict__ x,
    const float* __restrict__ w, const float* __restrict__ bias, float* __restrict__ out)
{
    const int t = threadIdx.x;
    const int tile = blockIdx.x;          // 64 tiles (8x8) of 16x16 over 128x128
    const int b = blockIdx.y;
    const int oy0 = (tile >> 3) << 4, ox0 = (tile & 7) << 4;
    const int tx = t & 15, ty = t >> 4;
    const int iy0 = 2 * oy0 - 1, ix0 = 2 * ox0 - 1;

    __shared__ float s_in[3 * 34 * 35];
    for (int i = t; i < 3 * 1156; i += 256) {
        int ci = i / 1156, rem = i % 1156, r = rem / 34, c = rem % 34;
        int gy = iy0 + r, gx = ix0 + c;
        float v = 0.f;
        if ((unsigned)gy < 256u && (unsigned)gx < 256u)
            v = x[((b * 3 + ci) * 256 + gy) * 256 + gx];
        s_in[(ci * 34 + r) * 35 + c] = v;
    }
    __syncthreads();

    float acc[64];
#pragma unroll
    for (int i = 0; i < 64; ++i) acc[i] = 0.f;
#pragma unroll
    for (int ci = 0; ci < 3; ++ci) {
        float v[16];
#pragma unroll
        for (int ky = 0; ky < 4; ++ky)
#pragma unroll
            for (int kx = 0; kx < 4; ++kx)
                v[ky * 4 + kx] = s_in[(ci * 34 + 2 * ty + ky) * 35 + 2 * tx + kx];
#pragma unroll
        for (int co = 0; co < 64; ++co)
#pragma unroll
            for (int k = 0; k < 16; ++k)
                acc[co] += v[k] * w[(co * 3 + ci) * 16 + k];
    }
#pragma unroll
    for (int co = 0; co < 64; ++co)
        out[((b * 64 + co) * 128 + oy0 + ty) * 128 + ox0 + tx] = frelu(acc[co] + bias[co]);
}

// ---------- encoder conv2: 4x4 s2 p1, 64->128, parity-split LDS, 16co/thread ----
__global__ __launch_bounds__(256) void k_ew2(const float* __restrict__ in,
    const float* __restrict__ w, const float* __restrict__ bias, float* __restrict__ out)
{
    const int t = threadIdx.x;
    const int tile = blockIdx.x;          // 16 tiles (4x4) of 16x16 over 64x64
    const int bcg = blockIdx.y;           // b*8 + cg   (16 co each)
    const int b = bcg >> 3, cg = bcg & 7;
    const int oy0 = (tile >> 2) << 4, ox0 = (tile & 3) << 4;
    const int tx = t & 15, ty = t >> 4;
    const int iy0 = 2 * oy0 - 1, ix0 = 2 * ox0 - 1;

    // parity-split: [ci4][py2][px2][17][18]; input (r,c) -> plane(r&1,c&1) at (r>>1,c>>1)
    __shared__ float s_in[4 * 4 * 17 * 18];

    constexpr int NS = 19;                // ceil(4*34*34 / 256)
    int goff[NS], loff[NS];
#pragma unroll
    for (int k = 0; k < NS; ++k) {
        int idx = t + (k << 8);
        if (idx < 4624) {
            int ci = idx / 1156, rem = idx % 1156, r = rem / 34, c = rem % 34;
            loff[k] = ((ci * 4 + (r & 1) * 2 + (c & 1)) * 17 + (r >> 1)) * 18 + (c >> 1);
            int gy = iy0 + r, gx = ix0 + c;
            goff[k] = ((unsigned)gy < 128u && (unsigned)gx < 128u)
                      ? ((b * 64 + ci) * 128 + gy) * 128 + gx : -1;
        } else { loff[k] = -1; goff[k] = -1; }
    }

    float acc[16];
#pragma unroll
    for (int i = 0; i < 16; ++i) acc[i] = 0.f;
    float pre[NS];
#pragma unroll
    for (int k = 0; k < NS; ++k) pre[k] = (goff[k] >= 0) ? in[goff[k]] : 0.f;
#pragma unroll
    for (int k = 0; k < NS; ++k) if (loff[k] >= 0) s_in[loff[k]] = pre[k];
    __syncthreads();

#pragma unroll 1
    for (int cc = 0; cc < 16; ++cc) {
        if (cc < 15) {
            const int coff = (cc + 1) * 4 * 16384;
#pragma unroll
            for (int k = 0; k < NS; ++k)
                pre[k] = (goff[k] >= 0) ? in[goff[k] + coff] : 0.f;
        }
#pragma unroll
        for (int ci = 0; ci < 4; ++ci) {
            float v[16];
#pragma unroll
            for (int ky = 0; ky < 4; ++ky)
#pragma unroll
                for (int kx = 0; kx < 4; ++kx)
                    v[ky * 4 + kx] = s_in[((ci * 4 + (ky & 1) * 2 + (kx & 1)) * 17
                                           + ty + (ky >> 1)) * 18 + tx + (kx >> 1)];
#pragma unroll
            for (int co = 0; co < 16; ++co)
#pragma unroll
                for (int k = 0; k < 16; ++k)
                    acc[co] += v[k] * w[((cg * 16 + co) * 64 + cc * 4 + ci) * 16 + k];
        }
        __syncthreads();
        if (cc < 15) {
#pragma unroll
            for (int k = 0; k < NS; ++k) if (loff[k] >= 0) s_in[loff[k]] = pre[k];
            __syncthreads();
        }
    }
#pragma unroll
    for (int co = 0; co < 16; ++co) {
        int oc = cg * 16 + co;
        out[((b * 128 + oc) * 64 + oy0 + ty) * 64 + ox0 + tx] = frelu(acc[co] + bias[oc]);
    }
}

// ---------- generic 3x3 s1 p1 conv at 64x64, reg-prefetch double buffer ---------
template<int CIN, int COUT, int COT, bool RELU, bool HASBIAS>
__global__ __launch_bounds__(256) void k_conv3(const float* __restrict__ in,
    const float* __restrict__ w, const float* __restrict__ bias, float* __restrict__ out)
{
    const int t = threadIdx.x;
    const int tile = blockIdx.x;          // 16 tiles (4x4) of 16x16
    constexpr int NCG = COUT / COT;
    const int bcg = blockIdx.y;
    const int b = bcg / NCG, cg = bcg % NCG;
    const int oy0 = (tile >> 2) << 4, ox0 = (tile & 3) << 4;
    const int tx = t & 15, ty = t >> 4;
    const int iy0 = oy0 - 1, ix0 = ox0 - 1;
    constexpr int NC = CIN / 8;

    __shared__ float s_in[8 * 18 * 19];
    constexpr int NS = 11;                // ceil(8*18*18 / 256)
    int goff[NS], loff[NS];
#pragma unroll
    for (int k = 0; k < NS; ++k) {
        int idx = t + (k << 8);
        if (idx < 2592) {
            int ci = idx / 324, rem = idx % 324, r = rem / 18, c = rem % 18;
            loff[k] = (ci * 18 + r) * 19 + c;
            int gy = iy0 + r, gx = ix0 + c;
            goff[k] = ((unsigned)gy < 64u && (unsigned)gx < 64u)
                      ? ((b * CIN + ci) * 64 + gy) * 64 + gx : -1;
        } else { loff[k] = -1; goff[k] = -1; }
    }

    float acc[COT];
#pragma unroll
    for (int i = 0; i < COT; ++i) acc[i] = 0.f;
    float pre[NS];
#pragma unroll
    for (int k = 0; k < NS; ++k) pre[k] = (goff[k] >= 0) ? in[goff[k]] : 0.f;
#pragma unroll
    for (int k = 0; k < NS; ++k) if (loff[k] >= 0) s_in[loff[k]] = pre[k];
    __syncthreads();

#pragma unroll 1
    for (int cc = 0; cc < NC; ++cc) {
        if (cc < NC - 1) {
            const int coff = (cc + 1) * 8 * 4096;
#pragma unroll
            for (int k = 0; k < NS; ++k)
                pre[k] = (goff[k] >= 0) ? in[goff[k] + coff] : 0.f;
        }
#pragma unroll
        for (int ci = 0; ci < 8; ++ci) {
            float v[9];
#pragma unroll
            for (int ky = 0; ky < 3; ++ky)
#pragma unroll
                for (int kx = 0; kx < 3; ++kx)
                    v[ky * 3 + kx] = s_in[(ci * 18 + ty + ky) * 19 + tx + kx];
#pragma unroll
            for (int co = 0; co < COT; ++co)
#pragma unroll
                for (int k = 0; k < 9; ++k)
                    acc[co] += v[k] * w[((cg * COT + co) * CIN + cc * 8 + ci) * 9 + k];
        }
        __syncthreads();
        if (cc < NC - 1) {
#pragma unroll
            for (int k = 0; k < NS; ++k) if (loff[k] >= 0) s_in[loff[k]] = pre[k];
            __syncthreads();
        }
    }
#pragma unroll
    for (int co = 0; co < COT; ++co) {
        int oc = cg * COT + co;
        float vv = acc[co];
        if (HASBIAS) vv += bias[oc];
        if (RELU) vv = frelu(vv);
        out[((b * COUT + oc) * 64 + oy0 + ty) * 64 + ox0 + tx] = vv;
    }
}

// ---------- residual 1x1: x += relu(conv1x1(t)), 32->128 ------------------------
__global__ __launch_bounds__(256) void k_res1x1(const float* __restrict__ tin,
    const float* __restrict__ w, float* __restrict__ xbuf)
{
    int gid = blockIdx.x * 256 + threadIdx.x;   // 16 * 8 * 4096
    int px = gid & 4095;
    int cg = (gid >> 12) & 7;
    int b = gid >> 15;
    float acc[16];
#pragma unroll
    for (int i = 0; i < 16; ++i) acc[i] = 0.f;
#pragma unroll
    for (int ci = 0; ci < 32; ++ci) {
        float v = tin[(b * 32 + ci) * 4096 + px];
#pragma unroll
        for (int co = 0; co < 16; ++co)
            acc[co] += v * w[(cg * 16 + co) * 32 + ci];
    }
#pragma unroll
    for (int co = 0; co < 16; ++co) {
        int o = (b * 128 + cg * 16 + co) * 4096 + px;
        xbuf[o] = xbuf[o] + frelu(acc[co]);
    }
}

// ---------- VQ pass 1: direct (z-e)^2, exact reference semantics, 4 e-slices ----
__global__ __launch_bounds__(256) void k_vq1(const float* __restrict__ z,
    const float* __restrict__ emb, float* __restrict__ distb, int* __restrict__ idxb)
{
    const int gid = blockIdx.x * 256 + threadIdx.x;   // 262144
    const int px = gid & 65535, slice = gid >> 16;
    const int b = px >> 12, h = (px >> 6) & 63, wq = px & 63;
    float zr[64];
#pragma unroll
    for (int d = 0; d < 64; ++d)
        zr[d] = z[((b * 64 + d) * 64 + h) * 64 + wq];

    float best = 3.4e38f; int bi = 0;
    const int e0 = slice * 128;
#pragma unroll 1
    for (int e = 0; e < 128; ++e) {
        const float* er = emb + (e0 + e) * 64;        // block-uniform -> s_load
        float dist = 0.f;
#pragma unroll
        for (int d = 0; d < 64; ++d) {
            float df = zr[d] - er[d];
            dist += df * df;                           // single chain, ascending d
        }
        if (dist < best) { best = dist; bi = e0 + e; } // strict < -> first min
    }
    distb[gid] = best;
    idxb[gid] = bi;
}

// ---------- VQ pass 2: merge slices (ascending -> first-min tiebreak), loss part -
__global__ __launch_bounds__(256) void k_vq2(const float* __restrict__ distb,
    const int* __restrict__ idxb, int* __restrict__ idx, float* __restrict__ part)
{
    const int t = threadIdx.x;
    const int px = blockIdx.x * 256 + t;
    float best = distb[px]; int bi = idxb[px];
#pragma unroll
    for (int s2 = 1; s2 < 4; ++s2) {
        float d = distb[s2 * 65536 + px];
        int i2 = idxb[s2 * 65536 + px];
        if (d < best) { best = d; bi = i2; }
    }
    idx[px] = bi;
    float s = best;
#pragma unroll
    for (int off = 32; off > 0; off >>= 1) s += __shfl_down(s, off, 64);
    __shared__ float sw[4];
    if ((t & 63) == 0) sw[t >> 6] = s;
    __syncthreads();
    if (t == 0) part[blockIdx.x] = sw[0] + sw[1] + sw[2] + sw[3];
}

// ---------- build quantized NCHW via LDS transpose ------------------------------
__global__ __launch_bounds__(256) void k_qbuild(const int* __restrict__ idx,
    const float* __restrict__ emb, float* __restrict__ q)
{
    const int t = threadIdx.x;
    const int bh = blockIdx.x;            // b*64 + h
    const int b = bh >> 6, h = bh & 63;
    __shared__ int s_idx[64];
    __shared__ float s_e[64 * 65];
    if (t < 64) s_idx[t] = idx[(b << 12) | (h << 6) | t];
    __syncthreads();
#pragma unroll
    for (int k = 0; k < 16; ++k) {
        int i = t + (k << 8);
        int wq = i >> 6, d = i & 63;
        s_e[wq * 65 + d] = emb[s_idx[wq] * 64 + d];   // coalesced emb rows
    }
    __syncthreads();
#pragma unroll
    for (int k = 0; k < 16; ++k) {
        int i = t + (k << 8);
        int d = i >> 6, wq = i & 63;
        q[((b * 64 + d) * 64 + h) * 64 + wq] = s_e[wq * 65 + d];
    }
}

__global__ __launch_bounds__(256) void k_loss(const float* __restrict__ part,
    float* __restrict__ out)
{
    int t = threadIdx.x;
    float s = part[t];
#pragma unroll
    for (int off = 32; off > 0; off >>= 1) s += __shfl_down(s, off, 64);
    __shared__ float sw[4];
    if ((t & 63) == 0) sw[t >> 6] = s;
    __syncthreads();
    if (t == 0) out[3145728] = 1.25f * (sw[0] + sw[1] + sw[2] + sw[3]) / 4194304.0f;
}

// ---------- ConvTranspose2d k4 s2 p1 + relu; w layout (CIN,COUT,4,4) ------------
template<int CIN, int COUT, int COT, int OW>
__global__ __launch_bounds__(256) void k_convT(const float* __restrict__ in,
    const float* __restrict__ w, const float* __restrict__ bias, float* __restrict__ out)
{
    constexpr int IW = OW / 2;
    constexpr int TPR = OW / 32;
    const int t = threadIdx.x;
    const int tile = blockIdx.x;              // TPR^2 tiles of 32x32 out
    constexpr int NCG = COUT / COT;
    const int bcg = blockIdx.y;
    const int b = bcg / NCG, cg = bcg % NCG;
    const int oy0 = (tile / TPR) * 32, ox0 = (tile % TPR) * 32;
    const int tx = t & 15, ty = t >> 4;       // thread owns 2x2 out px
    const int iy0 = oy0 / 2 - 1, ix0 = ox0 / 2 - 1;
    constexpr int NC = CIN / 8;

    __shared__ float s_in[8 * 18 * 19];
    constexpr int NS = 11;
    int goff[NS], loff[NS];
#pragma unroll
    for (int k = 0; k < NS; ++k) {
        int idx = t + (k << 8);
        if (idx < 2592) {
            int ci = idx / 324, rem = idx % 324, r = rem / 18, c = rem % 18;
            loff[k] = (ci * 18 + r) * 19 + c;
            int gy = iy0 + r, gx = ix0 + c;
            goff[k] = ((unsigned)gy < (unsigned)IW && (unsigned)gx < (unsigned)IW)
                      ? ((b * CIN + ci) * IW + gy) * IW + gx : -1;
        } else { loff[k] = -1; goff[k] = -1; }
    }

    float acc[4][COT];
#pragma unroll
    for (int a = 0; a < 4; ++a)
#pragma unroll
        for (int c = 0; c < COT; ++c) acc[a][c] = 0.f;
    float pre[NS];
#pragma unroll
    for (int k = 0; k < NS; ++k) pre[k] = (goff[k] >= 0) ? in[goff[k]] : 0.f;
#pragma unroll
    for (int k = 0; k < NS; ++k) if (loff[k] >= 0) s_in[loff[k]] = pre[k];
    __syncthreads();

#pragma unroll 1
    for (int cc = 0; cc < NC; ++cc) {
        if (cc < NC - 1) {
            const int coff = (cc + 1) * 8 * IW * IW;
#pragma unroll
            for (int k = 0; k < NS; ++k)
                pre[k] = (goff[k] >= 0) ? in[goff[k] + coff] : 0.f;
        }
#pragma unroll
        for (int ci = 0; ci < 8; ++ci) {
            float rr[3][3];
#pragma unroll
            for (int dy = 0; dy < 3; ++dy)
#pragma unroll
                for (int dx = 0; dx < 3; ++dx)
                    rr[dy][dx] = s_in[(ci * 18 + ty + dy) * 19 + tx + dx];
#pragma unroll
            for (int co = 0; co < COT; ++co)
#pragma unroll
                for (int ky = 0; ky < 4; ++ky) {
                    const int py = 1 - (ky & 1);
                    const int dy = (ky == 0) ? 2 : (ky == 3) ? 0 : 1;
#pragma unroll
                    for (int kx = 0; kx < 4; ++kx) {
                        const int pxr = 1 - (kx & 1);
                        const int dx = (kx == 0) ? 2 : (kx == 3) ? 0 : 1;
                        acc[py * 2 + pxr][co] += rr[dy][dx]
                            * w[((cc * 8 + ci) * COUT + cg * COT + co) * 16 + ky * 4 + kx];
                    }
                }
        }
        __syncthreads();
        if (cc < NC - 1) {
#pragma unroll
            for (int k = 0; k < NS; ++k) if (loff[k] >= 0) s_in[loff[k]] = pre[k];
            __syncthreads();
        }
    }
    const int ye = oy0 + 2 * ty, xe = ox0 + 2 * tx;
#pragma unroll
    for (int py = 0; py < 2; ++py)
#pragma unroll
        for (int pxr = 0; pxr < 2; ++pxr)
#pragma unroll
            for (int co = 0; co < COT; ++co) {
                int oc = cg * COT + co;
                out[((b * COUT + oc) * OW + ye + py) * OW + xe + pxr] =
                    frelu(acc[py * 2 + pxr][co] + bias[oc]);
            }
}

extern "C" void kernel_launch(void* const* d_in, const int* in_sizes, int n_in,
                              void* d_out, int out_size, void* d_ws, size_t ws_size,
                              hipStream_t stream)
{
    (void)in_sizes; (void)n_in; (void)out_size; (void)ws_size;
    const float* x    = (const float*)d_in[0];
    const float* emb  = (const float*)d_in[1];
    const float* ew1  = (const float*)d_in[2];
    const float* eb1  = (const float*)d_in[3];
    const float* ew2  = (const float*)d_in[4];
    const float* eb2  = (const float*)d_in[5];
    const float* er1a = (const float*)d_in[6];
    const float* er1b = (const float*)d_in[7];
    const float* er2a = (const float*)d_in[8];
    const float* er2b = (const float*)d_in[9];
    const float* ew3w = (const float*)d_in[10];
    const float* eb3  = (const float*)d_in[11];
    const float* dw1  = (const float*)d_in[12];
    const float* db1  = (const float*)d_in[13];
    const float* dr1a = (const float*)d_in[14];
    const float* dr1b = (const float*)d_in[15];
    const float* dr2a = (const float*)d_in[16];
    const float* dr2b = (const float*)d_in[17];
    const float* dtw1 = (const float*)d_in[18];
    const float* dtb1 = (const float*)d_in[19];
    const float* dtw2 = (const float*)d_in[20];
    const float* dtb2 = (const float*)d_in[21];
    float* out = (float*)d_out;
    float* ws  = (float*)d_ws;

    float* A    = ws;                          // [16,64,128,128] h1; later convT1 out
    float* Bf   = ws + 16777216;               // [16,128,64,64]
    float* T    = ws;                          // [16,32,64,64]   (h1 dead after ew2)
    float* Z    = ws + 2097152;                // [16,64,64,64]
    float* Q    = ws + 6291456;                // [16,64,64,64]
    int*   IDX  = (int*)(ws + 10485760);       // 65536
    float* PART = ws + 10551296;               // 256
    float* DISTB= ws + 10552064;               // 4*65536
    int*   IDXB = (int*)(ws + 10814208);       // 4*65536

    k_ew1<<<dim3(64, 16), 256, 0, stream>>>(x, ew1, eb1, A);
    k_ew2<<<dim3(16, 128), 256, 0, stream>>>(A, ew2, eb2, Bf);
    k_conv3<128, 32, 8, true, false><<<dim3(16, 64), 256, 0, stream>>>(Bf, er1a, nullptr, T);
    k_res1x1<<<2048, 256, 0, stream>>>(T, er1b, Bf);
    k_conv3<128, 32, 8, true, false><<<dim3(16, 64), 256, 0, stream>>>(Bf, er2a, nullptr, T);
    k_res1x1<<<2048, 256, 0, stream>>>(T, er2b, Bf);
    k_conv3<128, 64, 16, false, true><<<dim3(16, 64), 256, 0, stream>>>(Bf, ew3w, eb3, Z);
    k_vq1<<<1024, 256, 0, stream>>>(Z, emb, DISTB, IDXB);
    k_vq2<<<256, 256, 0, stream>>>(DISTB, IDXB, IDX, PART);
    k_loss<<<1, 256, 0, stream>>>(PART, out);
    k_qbuild<<<1024, 256, 0, stream>>>(IDX, emb, Q);
    k_conv3<64, 128, 16, false, true><<<dim3(16, 128), 256, 0, stream>>>(Q, dw1, db1, Bf);
    k_conv3<128, 32, 8, true, false><<<dim3(16, 64), 256, 0, stream>>>(Bf, dr1a, nullptr, T);
    k_res1x1<<<2048, 256, 0, stream>>>(T, dr1b, Bf);
    k_conv3<128, 32, 8, true, false><<<dim3(16, 64), 256, 0, stream>>>(Bf, dr2a, nullptr, T);
    k_res1x1<<<2048, 256, 0, stream>>>(T, dr2b, Bf);
    k_convT<128, 64, 8, 128><<<dim3(16, 128), 256, 0, stream>>>(Bf, dtw1, dtb1, A);
    k_convT<64, 3, 3, 256><<<dim3(64, 16), 256, 0, stream>>>(A, dtw2, dtb2, out);
}

// Round 5
// 4155.584 us; speedup vs baseline: 1.9435x; 1.6554x over previous
//
#include <hip/hip_runtime.h>

static __device__ __forceinline__ float frelu(float v) { return v > 0.f ? v : 0.f; }

// ---------- encoder conv1: 4x4 s2 p1, 3->64, bias+relu, 256^2 -> 128^2 ----------
__global__ __launch_bounds__(256) void k_ew1(const float* __restrict__ x,
    const float* __restrict__ w, const float* __restrict__ bias, float* __restrict__ out)
{
    const int t = threadIdx.x;
    const int tile = blockIdx.x;          // 64 tiles (8x8) of 16x16 over 128x128
    const int b = blockIdx.y;
    const int oy0 = (tile >> 3) << 4, ox0 = (tile & 7) << 4;
    const int tx = t & 15, ty = t >> 4;
    const int iy0 = 2 * oy0 - 1, ix0 = 2 * ox0 - 1;

    __shared__ float s_in[3 * 34 * 35];
    for (int i = t; i < 3 * 1156; i += 256) {
        int ci = i / 1156, rem = i % 1156, r = rem / 34, c = rem % 34;
        int gy = iy0 + r, gx = ix0 + c;
        float v = 0.f;
        if ((unsigned)gy < 256u && (unsigned)gx < 256u)
            v = x[((b * 3 + ci) * 256 + gy) * 256 + gx];
        s_in[(ci * 34 + r) * 35 + c] = v;
    }
    __syncthreads();

    float acc[64];
#pragma unroll
    for (int i = 0; i < 64; ++i) acc[i] = 0.f;
#pragma unroll
    for (int ci = 0; ci < 3; ++ci) {
        float v[16];
#pragma unroll
        for (int ky = 0; ky < 4; ++ky)
#pragma unroll
            for (int kx = 0; kx < 4; ++kx)
                v[ky * 4 + kx] = s_in[(ci * 34 + 2 * ty + ky) * 35 + 2 * tx + kx];
#pragma unroll
        for (int co = 0; co < 64; ++co)
#pragma unroll
            for (int k = 0; k < 16; ++k)
                acc[co] += v[k] * w[(co * 3 + ci) * 16 + k];
    }
#pragma unroll
    for (int co = 0; co < 64; ++co)
        out[((b * 64 + co) * 128 + oy0 + ty) * 128 + ox0 + tx] = frelu(acc[co] + bias[co]);
}

// ---------- encoder conv2: 4x4 s2 p1, 64->128, parity-split LDS, 16co/thread ----
__global__ __launch_bounds__(256) void k_ew2(const float* __restrict__ in,
    const float* __restrict__ w, const float* __restrict__ bias, float* __restrict__ out)
{
    const int t = threadIdx.x;
    const int tile = blockIdx.x;          // 16 tiles (4x4) of 16x16 over 64x64
    const int bcg = blockIdx.y;           // b*8 + cg   (16 co each)
    const int b = bcg >> 3, cg = bcg & 7;
    const int oy0 = (tile >> 2) << 4, ox0 = (tile & 3) << 4;
    const int tx = t & 15, ty = t >> 4;
    const int iy0 = 2 * oy0 - 1, ix0 = 2 * ox0 - 1;

    __shared__ float s_in[4 * 4 * 17 * 18];

    constexpr int NS = 19;                // ceil(4*34*34 / 256)
    int goff[NS], loff[NS];
#pragma unroll
    for (int k = 0; k < NS; ++k) {
        int idx = t + (k << 8);
        if (idx < 4624) {
            int ci = idx / 1156, rem = idx % 1156, r = rem / 34, c = rem % 34;
            loff[k] = ((ci * 4 + (r & 1) * 2 + (c & 1)) * 17 + (r >> 1)) * 18 + (c >> 1);
            int gy = iy0 + r, gx = ix0 + c;
            goff[k] = ((unsigned)gy < 128u && (unsigned)gx < 128u)
                      ? ((b * 64 + ci) * 128 + gy) * 128 + gx : -1;
        } else { loff[k] = -1; goff[k] = -1; }
    }

    float acc[16];
#pragma unroll
    for (int i = 0; i < 16; ++i) acc[i] = 0.f;
    float pre[NS];
#pragma unroll
    for (int k = 0; k < NS; ++k) pre[k] = (goff[k] >= 0) ? in[goff[k]] : 0.f;
#pragma unroll
    for (int k = 0; k < NS; ++k) if (loff[k] >= 0) s_in[loff[k]] = pre[k];
    __syncthreads();

#pragma unroll 1
    for (int cc = 0; cc < 16; ++cc) {
        if (cc < 15) {
            const int coff = (cc + 1) * 4 * 16384;
#pragma unroll
            for (int k = 0; k < NS; ++k)
                pre[k] = (goff[k] >= 0) ? in[goff[k] + coff] : 0.f;
        }
#pragma unroll
        for (int ci = 0; ci < 4; ++ci) {
            float v[16];
#pragma unroll
            for (int ky = 0; ky < 4; ++ky)
#pragma unroll
                for (int kx = 0; kx < 4; ++kx)
                    v[ky * 4 + kx] = s_in[((ci * 4 + (ky & 1) * 2 + (kx & 1)) * 17
                                           + ty + (ky >> 1)) * 18 + tx + (kx >> 1)];
#pragma unroll
            for (int co = 0; co < 16; ++co)
#pragma unroll
                for (int k = 0; k < 16; ++k)
                    acc[co] += v[k] * w[((cg * 16 + co) * 64 + cc * 4 + ci) * 16 + k];
        }
        __syncthreads();
        if (cc < 15) {
#pragma unroll
            for (int k = 0; k < NS; ++k) if (loff[k] >= 0) s_in[loff[k]] = pre[k];
            __syncthreads();
        }
    }
#pragma unroll
    for (int co = 0; co < 16; ++co) {
        int oc = cg * 16 + co;
        out[((b * 128 + oc) * 64 + oy0 + ty) * 64 + ox0 + tx] = frelu(acc[co] + bias[oc]);
    }
}

// ---------- 3x3 s1 p1 conv at 64x64, thread = 1x4 px, 8 co (weight reuse 4x) ----
// Per-acc summation order: cc(8-chunk asc) -> ci asc -> ky asc -> kx asc  (bitwise
// identical to previous passing kernels -> safe on the encoder path).
template<int CIN, int COUT, bool RELU, bool HASBIAS>
__global__ __launch_bounds__(256) void k_gconvW4(const float* __restrict__ in,
    const float* __restrict__ w, const float* __restrict__ bias, float* __restrict__ out)
{
    constexpr int NCG = COUT / 8;
    const int t = threadIdx.x;
    const int ty = t >> 4, tx = t & 15;   // 16 x 16
    const int rt = blockIdx.x;            // 4 row-tiles of 16 rows
    const int bcg = blockIdx.y;
    const int b = bcg / NCG, cg = bcg % NCG;
    const int y0 = rt << 4;
    const int oc0 = cg << 3;

    __shared__ __align__(16) float s_a[8][18][72];  // global col gc -> L = gc+4

    float acc[4][8];
#pragma unroll
    for (int j = 0; j < 4; ++j)
#pragma unroll
        for (int c = 0; c < 8; ++c) acc[j][c] = 0.f;

#pragma unroll 1
    for (int cc = 0; cc < CIN / 8; ++cc) {
        __syncthreads();
        for (int ci = 0; ci < 8; ++ci) {
            for (int j = t; j < 18 * 66; j += 256) {
                int r = j / 66, c = j % 66;
                int gy = y0 - 1 + r, gx = c - 1;
                float v = 0.f;
                if ((unsigned)gy < 64u && (unsigned)gx < 64u)
                    v = in[((b * CIN + cc * 8 + ci) * 64 + gy) * 64 + gx];
                s_a[ci][r][c + 3] = v;
            }
        }
        __syncthreads();
        for (int ci = 0; ci < 8; ++ci) {
            float p[3][6];
#pragma unroll
            for (int rr = 0; rr < 3; ++rr) {
                const float* rowp = &s_a[ci][ty + rr][4 * tx + 3];
                p[rr][0] = rowp[0];
                float4 m = *reinterpret_cast<const float4*>(rowp + 1);
                p[rr][1] = m.x; p[rr][2] = m.y; p[rr][3] = m.z; p[rr][4] = m.w;
                p[rr][5] = rowp[5];
            }
            const float* wp = &w[(oc0 * CIN + cc * 8 + ci) * 9];
#pragma unroll
            for (int ky = 0; ky < 3; ++ky)
#pragma unroll
                for (int kx = 0; kx < 3; ++kx) {
#pragma unroll
                    for (int co = 0; co < 8; ++co) {
                        float wv = wp[co * CIN * 9 + ky * 3 + kx];
#pragma unroll
                        for (int j = 0; j < 4; ++j)
                            acc[j][co] += p[ky][j + kx] * wv;
                    }
                }
        }
    }
#pragma unroll
    for (int co = 0; co < 8; ++co) {
        int oc = oc0 + co;
        float bv = HASBIAS ? bias[oc] : 0.f;
#pragma unroll
        for (int j = 0; j < 4; ++j) {
            float v = acc[j][co] + bv;
            if (RELU) v = frelu(v);
            out[((b * COUT + oc) * 64 + y0 + ty) * 64 + 4 * tx + j] = v;
        }
    }
}

// ---------- 3x3 s1 p1 conv at 64x64, thread = 2x2 px, 8 co (for COUT=32) --------
template<int CIN, int COUT, bool RELU, bool HASBIAS>
__global__ __launch_bounds__(256) void k_gconvQ22(const float* __restrict__ in,
    const float* __restrict__ w, const float* __restrict__ bias, float* __restrict__ out)
{
    constexpr int NCG = COUT / 8;
    const int t = threadIdx.x;
    const int ty = t >> 5, tx = t & 31;   // 8 x 32 -> 2x2 px each => 16 x 64 tile
    const int rt = blockIdx.x;            // 4 row-tiles
    const int bcg = blockIdx.y;
    const int b = bcg / NCG, cg = bcg % NCG;
    const int y0 = rt << 4;
    const int oc0 = cg << 3;

    __shared__ __align__(16) float s_a[8][18][68];  // global col gc -> L = gc+1

    float acc[4][8];
#pragma unroll
    for (int j = 0; j < 4; ++j)
#pragma unroll
        for (int c = 0; c < 8; ++c) acc[j][c] = 0.f;

#pragma unroll 1
    for (int cc = 0; cc < CIN / 8; ++cc) {
        __syncthreads();
        for (int ci = 0; ci < 8; ++ci) {
            for (int j = t; j < 18 * 66; j += 256) {
                int r = j / 66, c = j % 66;
                int gy = y0 - 1 + r, gx = c - 1;
                float v = 0.f;
                if ((unsigned)gy < 64u && (unsigned)gx < 64u)
                    v = in[((b * CIN + cc * 8 + ci) * 64 + gy) * 64 + gx];
                s_a[ci][r][c] = v;
            }
        }
        __syncthreads();
        for (int ci = 0; ci < 8; ++ci) {
            float p[4][4];
#pragma unroll
            for (int rr = 0; rr < 4; ++rr)
#pragma unroll
                for (int s = 0; s < 4; ++s)
                    p[rr][s] = s_a[ci][2 * ty + rr][2 * tx + s];
            const float* wp = &w[(oc0 * CIN + cc * 8 + ci) * 9];
#pragma unroll
            for (int ky = 0; ky < 3; ++ky)
#pragma unroll
                for (int kx = 0; kx < 3; ++kx) {
#pragma unroll
                    for (int co = 0; co < 8; ++co) {
                        float wv = wp[co * CIN * 9 + ky * 3 + kx];
#pragma unroll
                        for (int jr = 0; jr < 2; ++jr)
#pragma unroll
                            for (int jc = 0; jc < 2; ++jc)
                                acc[jr * 2 + jc][co] += p[jr + ky][jc + kx] * wv;
                    }
                }
        }
    }
#pragma unroll
    for (int co = 0; co < 8; ++co) {
        int oc = oc0 + co;
        float bv = HASBIAS ? bias[oc] : 0.f;
#pragma unroll
        for (int jr = 0; jr < 2; ++jr)
#pragma unroll
            for (int jc = 0; jc < 2; ++jc) {
                float v = acc[jr * 2 + jc][co] + bv;
                if (RELU) v = frelu(v);
                out[((b * COUT + oc) * 64 + y0 + 2 * ty + jr) * 64 + 2 * tx + jc] = v;
            }
    }
}

// ---------- residual 1x1: x += relu(conv1x1(t)), 32->128 ------------------------
__global__ __launch_bounds__(256) void k_res1x1(const float* __restrict__ tin,
    const float* __restrict__ w, float* __restrict__ xbuf)
{
    int gid = blockIdx.x * 256 + threadIdx.x;   // 16 * 8 * 4096
    int px = gid & 4095;
    int cg = (gid >> 12) & 7;
    int b = gid >> 15;
    float acc[16];
#pragma unroll
    for (int i = 0; i < 16; ++i) acc[i] = 0.f;
#pragma unroll
    for (int ci = 0; ci < 32; ++ci) {
        float v = tin[(b * 32 + ci) * 4096 + px];
#pragma unroll
        for (int co = 0; co < 16; ++co)
            acc[co] += v * w[(cg * 16 + co) * 32 + ci];
    }
#pragma unroll
    for (int co = 0; co < 16; ++co) {
        int o = (b * 128 + cg * 16 + co) * 4096 + px;
        xbuf[o] = xbuf[o] + frelu(acc[co]);
    }
}

// ---------- VQ pass 1: direct (z-e)^2, exact reference semantics, 4 e-slices ----
__global__ __launch_bounds__(256) void k_vq1(const float* __restrict__ z,
    const float* __restrict__ emb, float* __restrict__ distb, int* __restrict__ idxb)
{
    const int gid = blockIdx.x * 256 + threadIdx.x;   // 262144
    const int px = gid & 65535, slice = gid >> 16;
    const int b = px >> 12, h = (px >> 6) & 63, wq = px & 63;
    float zr[64];
#pragma unroll
    for (int d = 0; d < 64; ++d)
        zr[d] = z[((b * 64 + d) * 64 + h) * 64 + wq];

    float best = 3.4e38f; int bi = 0;
    const int e0 = slice * 128;
#pragma unroll 1
    for (int e = 0; e < 128; ++e) {
        const float* er = emb + (e0 + e) * 64;        // block-uniform -> s_load
        float dist = 0.f;
#pragma unroll
        for (int d = 0; d < 64; ++d) {
            float df = zr[d] - er[d];
            dist += df * df;                           // single chain, ascending d
        }
        if (dist < best) { best = dist; bi = e0 + e; } // strict < -> first min
    }
    distb[gid] = best;
    idxb[gid] = bi;
}

// ---------- VQ pass 2: merge slices (ascending -> first-min tiebreak), loss part -
__global__ __launch_bounds__(256) void k_vq2(const float* __restrict__ distb,
    const int* __restrict__ idxb, int* __restrict__ idx, float* __restrict__ part)
{
    const int t = threadIdx.x;
    const int px = blockIdx.x * 256 + t;
    float best = distb[px]; int bi = idxb[px];
#pragma unroll
    for (int s2 = 1; s2 < 4; ++s2) {
        float d = distb[s2 * 65536 + px];
        int i2 = idxb[s2 * 65536 + px];
        if (d < best) { best = d; bi = i2; }
    }
    idx[px] = bi;
    float s = best;
#pragma unroll
    for (int off = 32; off > 0; off >>= 1) s += __shfl_down(s, off, 64);
    __shared__ float sw[4];
    if ((t & 63) == 0) sw[t >> 6] = s;
    __syncthreads();
    if (t == 0) part[blockIdx.x] = sw[0] + sw[1] + sw[2] + sw[3];
}

// ---------- build quantized NCHW via LDS transpose ------------------------------
__global__ __launch_bounds__(256) void k_qbuild(const int* __restrict__ idx,
    const float* __restrict__ emb, float* __restrict__ q)
{
    const int t = threadIdx.x;
    const int bh = blockIdx.x;            // b*64 + h
    const int b = bh >> 6, h = bh & 63;
    __shared__ int s_idx[64];
    __shared__ float s_e[64 * 65];
    if (t < 64) s_idx[t] = idx[(b << 12) | (h << 6) | t];
    __syncthreads();
#pragma unroll
    for (int k = 0; k < 16; ++k) {
        int i = t + (k << 8);
        int wq = i >> 6, d = i & 63;
        s_e[wq * 65 + d] = emb[s_idx[wq] * 64 + d];   // coalesced emb rows
    }
    __syncthreads();
#pragma unroll
    for (int k = 0; k < 16; ++k) {
        int i = t + (k << 8);
        int d = i >> 6, wq = i & 63;
        q[((b * 64 + d) * 64 + h) * 64 + wq] = s_e[wq * 65 + d];
    }
}

__global__ __launch_bounds__(256) void k_loss(const float* __restrict__ part,
    float* __restrict__ out)
{
    int t = threadIdx.x;
    float s = part[t];
#pragma unroll
    for (int off = 32; off > 0; off >>= 1) s += __shfl_down(s, off, 64);
    __shared__ float sw[4];
    if ((t & 63) == 0) sw[t >> 6] = s;
    __syncthreads();
    if (t == 0) out[3145728] = 1.25f * (sw[0] + sw[1] + sw[2] + sw[3]) / 4194304.0f;
}

// ---------- ConvTranspose2d k4 s2 p1 + bias + relu, as 4 parity sub-convs -------
// w layout (CIN, COUT, 4, 4).  blockIdx.z = parity (py*2+px).
// Each thread: 4 horizontal in-positions -> 4 out px of this parity, COT co.
template<int CIN, int COUT, int COT, int IW>
__global__ __launch_bounds__(256) void k_convTP(const float* __restrict__ in,
    const float* __restrict__ w, const float* __restrict__ bias, float* __restrict__ out)
{
    constexpr int NTX = IW / 4;           // threads along x
    constexpr int NTY = 256 / NTX;        // rows per tile
    constexpr int NCG = COUT / COT;
    constexpr int STR = IW + 8;           // LDS row stride (mult of 4)
    const int t = threadIdx.x;
    const int ty = t / NTX, tx = t % NTX;
    const int rt = blockIdx.x;            // IW/NTY row tiles
    const int bcg = blockIdx.y;
    const int b = bcg / NCG, cg = bcg % NCG;
    const int par = blockIdx.z;
    const int py = par >> 1, px = par & 1;
    const int y0 = rt * NTY;
    const int pr0 = y0 - 1 + py;          // first staged global row
    const int oc0 = cg * COT;

    __shared__ __align__(16) float s_a[8][NTY + 1][STR];  // L = gc + 1 - px

    float acc[4][COT];
#pragma unroll
    for (int j = 0; j < 4; ++j)
#pragma unroll
        for (int c = 0; c < COT; ++c) acc[j][c] = 0.f;

    // tap tables for this parity: first ky/kx maps to row ty+1 / col j+1
    const int kyA = py ? 0 : 1, kyB = py ? 2 : 3;
    const int kxA = px ? 0 : 1, kxB = px ? 2 : 3;

#pragma unroll 1
    for (int cc = 0; cc < CIN / 8; ++cc) {
        __syncthreads();
        for (int ci = 0; ci < 8; ++ci) {
            for (int j = t; j < (NTY + 1) * (IW + 1); j += 256) {
                int r = j / (IW + 1), c = j % (IW + 1);
                int gy = pr0 + r, gx = c - 1 + px;
                float v = 0.f;
                if ((unsigned)gy < (unsigned)IW && (unsigned)gx < (unsigned)IW)
                    v = in[((b * CIN + cc * 8 + ci) * IW + gy) * IW + gx];
                s_a[ci][r][c] = v;
            }
        }
        __syncthreads();
        for (int ci = 0; ci < 8; ++ci) {
            float p0[5], p1[5];           // rows ty (second ky), ty+1 (first ky)
            {
                const float* r0 = &s_a[ci][ty][4 * tx];
                const float* r1 = &s_a[ci][ty + 1][4 * tx];
                float4 m0 = *reinterpret_cast<const float4*>(r0);
                float4 m1 = *reinterpret_cast<const float4*>(r1);
                p0[0] = m0.x; p0[1] = m0.y; p0[2] = m0.z; p0[3] = m0.w; p0[4] = r0[4];
                p1[0] = m1.x; p1[1] = m1.y; p1[2] = m1.z; p1[3] = m1.w; p1[4] = r1[4];
            }
            const int wbase = ((cc * 8 + ci) * COUT + oc0) * 16;
#pragma unroll
            for (int kyi = 0; kyi < 2; ++kyi) {
                const int ky = kyi ? kyB : kyA;
                const float* pr = kyi ? p0 : p1;
#pragma unroll
                for (int kxi = 0; kxi < 2; ++kxi) {
                    const int kx = kxi ? kxB : kxA;
                    const int cs = 1 - kxi;
#pragma unroll
                    for (int co = 0; co < COT; ++co) {
                        float wv = w[wbase + co * 16 + ky * 4 + kx];
#pragma unroll
                        for (int j = 0; j < 4; ++j)
                            acc[j][co] += pr[j + cs] * wv;
                    }
                }
            }
        }
    }
    const int oy = 2 * (y0 + ty) + py;
#pragma unroll
    for (int co = 0; co < COT; ++co) {
        int oc = oc0 + co;
        float bv = bias[oc];
#pragma unroll
        for (int j = 0; j < 4; ++j) {
            int ox = 8 * tx + 2 * j + px;
            out[((b * COUT + oc) * (2 * IW) + oy) * (2 * IW) + ox] =
                frelu(acc[j][co] + bv);
        }
    }
}

extern "C" void kernel_launch(void* const* d_in, const int* in_sizes, int n_in,
                              void* d_out, int out_size, void* d_ws, size_t ws_size,
                              hipStream_t stream)
{
    (void)in_sizes; (void)n_in; (void)out_size; (void)ws_size;
    const float* x    = (const float*)d_in[0];
    const float* emb  = (const float*)d_in[1];
    const float* ew1  = (const float*)d_in[2];
    const float* eb1  = (const float*)d_in[3];
    const float* ew2  = (const float*)d_in[4];
    const float* eb2  = (const float*)d_in[5];
    const float* er1a = (const float*)d_in[6];
    const float* er1b = (const float*)d_in[7];
    const float* er2a = (const float*)d_in[8];
    const float* er2b = (const float*)d_in[9];
    const float* ew3w = (const float*)d_in[10];
    const float* eb3  = (const float*)d_in[11];
    const float* dw1  = (const float*)d_in[12];
    const float* db1  = (const float*)d_in[13];
    const float* dr1a = (const float*)d_in[14];
    const float* dr1b = (const float*)d_in[15];
    const float* dr2a = (const float*)d_in[16];
    const float* dr2b = (const float*)d_in[17];
    const float* dtw1 = (const float*)d_in[18];
    const float* dtb1 = (const float*)d_in[19];
    const float* dtw2 = (const float*)d_in[20];
    const float* dtb2 = (const float*)d_in[21];
    float* out = (float*)d_out;
    float* ws  = (float*)d_ws;

    float* A    = ws;                          // [16,64,128,128] h1; later convT1 out
    float* Bf   = ws + 16777216;               // [16,128,64,64]
    float* T    = ws;                          // [16,32,64,64]   (h1 dead after ew2)
    float* Z    = ws + 2097152;                // [16,64,64,64]
    float* Q    = ws + 6291456;                // [16,64,64,64]
    int*   IDX  = (int*)(ws + 10485760);       // 65536
    float* PART = ws + 10551296;               // 256
    float* DISTB= ws + 10552064;               // 4*65536
    int*   IDXB = (int*)(ws + 10814208);       // 4*65536

    k_ew1<<<dim3(64, 16), 256, 0, stream>>>(x, ew1, eb1, A);
    k_ew2<<<dim3(16, 128), 256, 0, stream>>>(A, ew2, eb2, Bf);
    k_gconvQ22<128, 32, true, false><<<dim3(4, 64), 256, 0, stream>>>(Bf, er1a, nullptr, T);
    k_res1x1<<<2048, 256, 0, stream>>>(T, er1b, Bf);
    k_gconvQ22<128, 32, true, false><<<dim3(4, 64), 256, 0, stream>>>(Bf, er2a, nullptr, T);
    k_res1x1<<<2048, 256, 0, stream>>>(T, er2b, Bf);
    k_gconvW4<128, 64, false, true><<<dim3(4, 128), 256, 0, stream>>>(Bf, ew3w, eb3, Z);
    k_vq1<<<1024, 256, 0, stream>>>(Z, emb, DISTB, IDXB);
    k_vq2<<<256, 256, 0, stream>>>(DISTB, IDXB, IDX, PART);
    k_loss<<<1, 256, 0, stream>>>(PART, out);
    k_qbuild<<<1024, 256, 0, stream>>>(IDX, emb, Q);
    k_gconvW4<64, 128, false, true><<<dim3(4, 256), 256, 0, stream>>>(Q, dw1, db1, Bf);
    k_gconvQ22<128, 32, true, false><<<dim3(4, 64), 256, 0, stream>>>(Bf, dr1a, nullptr, T);
    k_res1x1<<<2048, 256, 0, stream>>>(T, dr1b, Bf);
    k_gconvQ22<128, 32, true, false><<<dim3(4, 64), 256, 0, stream>>>(Bf, dr2a, nullptr, T);
    k_res1x1<<<2048, 256, 0, stream>>>(T, dr2b, Bf);
    k_convTP<128, 64, 8, 64><<<dim3(4, 128, 4), 256, 0, stream>>>(Bf, dtw1, dtb1, A);
    k_convTP<64, 3, 3, 128><<<dim3(16, 16, 4), 256, 0, stream>>>(A, dtw2, dtb2, out);
}

// Round 7
// 3889.840 us; speedup vs baseline: 2.0763x; 1.0683x over previous
//
#include <hip/hip_runtime.h>

static __device__ __forceinline__ float frelu(float v) { return v > 0.f ? v : 0.f; }

// ---------- encoder conv1: 4x4 s2 p1, 3->64, bias+relu, 256^2 -> 128^2 ----------
__global__ __launch_bounds__(256) void k_ew1(const float* __restrict__ x,
    const float* __restrict__ w, const float* __restrict__ bias, float* __restrict__ out)
{
    const int t = threadIdx.x;
    const int tile = blockIdx.x;          // 64 tiles (8x8) of 16x16 over 128x128
    const int b = blockIdx.y;
    const int oy0 = (tile >> 3) << 4, ox0 = (tile & 7) << 4;
    const int tx = t & 15, ty = t >> 4;
    const int iy0 = 2 * oy0 - 1, ix0 = 2 * ox0 - 1;

    __shared__ float s_in[3 * 34 * 35];
    for (int i = t; i < 3 * 1156; i += 256) {
        int ci = i / 1156, rem = i % 1156, r = rem / 34, c = rem % 34;
        int gy = iy0 + r, gx = ix0 + c;
        float v = 0.f;
        if ((unsigned)gy < 256u && (unsigned)gx < 256u)
            v = x[((b * 3 + ci) * 256 + gy) * 256 + gx];
        s_in[(ci * 34 + r) * 35 + c] = v;
    }
    __syncthreads();

    float acc[64];
#pragma unroll
    for (int i = 0; i < 64; ++i) acc[i] = 0.f;
#pragma unroll
    for (int ci = 0; ci < 3; ++ci) {
        float v[16];
#pragma unroll
        for (int ky = 0; ky < 4; ++ky)
#pragma unroll
            for (int kx = 0; kx < 4; ++kx)
                v[ky * 4 + kx] = s_in[(ci * 34 + 2 * ty + ky) * 35 + 2 * tx + kx];
#pragma unroll
        for (int co = 0; co < 64; ++co)
#pragma unroll
            for (int k = 0; k < 16; ++k)
                acc[co] += v[k] * w[(co * 3 + ci) * 16 + k];
    }
#pragma unroll
    for (int co = 0; co < 64; ++co)
        out[((b * 64 + co) * 128 + oy0 + ty) * 128 + ox0 + tx] = frelu(acc[co] + bias[co]);
}

// ---------- encoder conv2: 4x4 s2 p1, 64->128, parity planes, 4px x 8co ---------
// Per-acc summation order: channel asc (cc*2+ci), then ky asc, kx asc -> bitwise
// identical to the round-4/5 passing ew2 (z and VQ indices unchanged).
__global__ __launch_bounds__(256) void k_ew2(const float* __restrict__ in,
    const float* __restrict__ w, const float* __restrict__ bias, float* __restrict__ out)
{
    const int t = threadIdx.x;
    const int ty = t >> 4, tx = t & 15;   // 16 x 16 threads; thread = 1x4 out px
    const int rt = blockIdx.x;            // 4 row tiles of 16 rows over 64x64 out
    const int bcg = blockIdx.y;           // b*16 + cg  (8 co each)
    const int b = bcg >> 4, cg = bcg & 15;
    const int y0 = rt << 4;
    const int oc0 = cg << 3;

    // parity planes: [ci2][pr*2+pc][17][68]; plane(pr,pc) row r col c holds
    // input (2*(y0+r)-pr, 2*c-pc).  65 cols used, stride 68.
    __shared__ __align__(16) float s_a[2][4][17][68];

    float acc[4][8];
#pragma unroll
    for (int j = 0; j < 4; ++j)
#pragma unroll
        for (int c = 0; c < 8; ++c) acc[j][c] = 0.f;

#pragma unroll 1
    for (int cc = 0; cc < 32; ++cc) {     // 2 input channels per chunk
        __syncthreads();
        for (int ci = 0; ci < 2; ++ci) {
            const float* src = in + (size_t)((b * 64 + cc * 2 + ci) * 128) * 128;
#pragma unroll
            for (int pl = 0; pl < 4; ++pl) {
                const int pr = pl >> 1, pc = pl & 1;
                for (int j = t; j < 1105; j += 256) {        // 17*65
                    int r = j / 65, c = j % 65;
                    int gy = 2 * (y0 + r) - pr;
                    int gx = 2 * c - pc;
                    float v = 0.f;
                    if ((unsigned)gy < 128u && (unsigned)gx < 128u)
                        v = src[gy * 128 + gx];
                    s_a[ci][pl][r][c] = v;
                }
            }
        }
        __syncthreads();
#pragma unroll
        for (int ci = 0; ci < 2; ++ci) {
            float pv[4][2][5];
#pragma unroll
            for (int pl = 0; pl < 4; ++pl)
#pragma unroll
                for (int rr = 0; rr < 2; ++rr) {
                    const float* rp = &s_a[ci][pl][ty + rr][4 * tx];
                    float4 m = *reinterpret_cast<const float4*>(rp);
                    pv[pl][rr][0] = m.x; pv[pl][rr][1] = m.y;
                    pv[pl][rr][2] = m.z; pv[pl][rr][3] = m.w;
                    pv[pl][rr][4] = rp[4];
                }
            const float* wp = &w[(oc0 * 64 + cc * 2 + ci) * 16];
#pragma unroll
            for (int ky = 0; ky < 4; ++ky) {
                const int pr = 1 - (ky & 1);      // ky 0,2 -> odd input row plane
                const int rr = ky >> 1;           // ky 0,1 -> row ty; 2,3 -> ty+1
#pragma unroll
                for (int kx = 0; kx < 4; ++kx) {
                    const int pc = 1 - (kx & 1);
                    const int cs = kx >> 1;
                    const int pl = pr * 2 + pc;
#pragma unroll
                    for (int co = 0; co < 8; ++co) {
                        float wv = wp[co * 1024 + ky * 4 + kx];
#pragma unroll
                        for (int j = 0; j < 4; ++j)
                            acc[j][co] += pv[pl][rr][j + cs] * wv;
                    }
                }
            }
        }
    }
#pragma unroll
    for (int co = 0; co < 8; ++co) {
        int oc = oc0 + co;
        float bv = bias[oc];
#pragma unroll
        for (int j = 0; j < 4; ++j)
            out[((b * 128 + oc) * 64 + y0 + ty) * 64 + 4 * tx + j] = frelu(acc[j][co] + bv);
    }
}

// ---------- 3x3 s1 p1 conv at 64x64, thread = 1x4 px, 8 co (weight reuse 4x) ----
template<int CIN, int COUT, bool RELU, bool HASBIAS>
__global__ __launch_bounds__(256) void k_gconvW4(const float* __restrict__ in,
    const float* __restrict__ w, const float* __restrict__ bias, float* __restrict__ out)
{
    constexpr int NCG = COUT / 8;
    const int t = threadIdx.x;
    const int ty = t >> 4, tx = t & 15;   // 16 x 16
    const int rt = blockIdx.x;            // 4 row-tiles of 16 rows
    const int bcg = blockIdx.y;
    const int b = bcg / NCG, cg = bcg % NCG;
    const int y0 = rt << 4;
    const int oc0 = cg << 3;

    __shared__ __align__(16) float s_a[8][18][72];  // global col gc -> L = gc+4

    float acc[4][8];
#pragma unroll
    for (int j = 0; j < 4; ++j)
#pragma unroll
        for (int c = 0; c < 8; ++c) acc[j][c] = 0.f;

#pragma unroll 1
    for (int cc = 0; cc < CIN / 8; ++cc) {
        __syncthreads();
        for (int ci = 0; ci < 8; ++ci) {
            for (int j = t; j < 18 * 66; j += 256) {
                int r = j / 66, c = j % 66;
                int gy = y0 - 1 + r, gx = c - 1;
                float v = 0.f;
                if ((unsigned)gy < 64u && (unsigned)gx < 64u)
                    v = in[((b * CIN + cc * 8 + ci) * 64 + gy) * 64 + gx];
                s_a[ci][r][c + 3] = v;
            }
        }
        __syncthreads();
        for (int ci = 0; ci < 8; ++ci) {
            float p[3][6];
#pragma unroll
            for (int rr = 0; rr < 3; ++rr) {
                const float* rowp = &s_a[ci][ty + rr][4 * tx + 3];
                p[rr][0] = rowp[0];
                float4 m = *reinterpret_cast<const float4*>(rowp + 1);
                p[rr][1] = m.x; p[rr][2] = m.y; p[rr][3] = m.z; p[rr][4] = m.w;
                p[rr][5] = rowp[5];
            }
            const float* wp = &w[(oc0 * CIN + cc * 8 + ci) * 9];
#pragma unroll
            for (int ky = 0; ky < 3; ++ky)
#pragma unroll
                for (int kx = 0; kx < 3; ++kx) {
#pragma unroll
                    for (int co = 0; co < 8; ++co) {
                        float wv = wp[co * CIN * 9 + ky * 3 + kx];
#pragma unroll
                        for (int j = 0; j < 4; ++j)
                            acc[j][co] += p[ky][j + kx] * wv;
                    }
                }
        }
    }
#pragma unroll
    for (int co = 0; co < 8; ++co) {
        int oc = oc0 + co;
        float bv = HASBIAS ? bias[oc] : 0.f;
#pragma unroll
        for (int j = 0; j < 4; ++j) {
            float v = acc[j][co] + bv;
            if (RELU) v = frelu(v);
            out[((b * COUT + oc) * 64 + y0 + ty) * 64 + 4 * tx + j] = v;
        }
    }
}

// ---------- 3x3 s1 p1 conv at 64x64, thread = 2x2 px, 8 co (for COUT=32) --------
template<int CIN, int COUT, bool RELU, bool HASBIAS>
__global__ __launch_bounds__(256) void k_gconvQ22(const float* __restrict__ in,
    const float* __restrict__ w, const float* __restrict__ bias, float* __restrict__ out)
{
    constexpr int NCG = COUT / 8;
    const int t = threadIdx.x;
    const int ty = t >> 5, tx = t & 31;   // 8 x 32 -> 2x2 px each => 16 x 64 tile
    const int rt = blockIdx.x;            // 4 row-tiles
    const int bcg = blockIdx.y;
    const int b = bcg / NCG, cg = bcg % NCG;
    const int y0 = rt << 4;
    const int oc0 = cg << 3;

    __shared__ __align__(16) float s_a[8][18][68];

    float acc[4][8];
#pragma unroll
    for (int j = 0; j < 4; ++j)
#pragma unroll
        for (int c = 0; c < 8; ++c) acc[j][c] = 0.f;

#pragma unroll 1
    for (int cc = 0; cc < CIN / 8; ++cc) {
        __syncthreads();
        for (int ci = 0; ci < 8; ++ci) {
            for (int j = t; j < 18 * 66; j += 256) {
                int r = j / 66, c = j % 66;
                int gy = y0 - 1 + r, gx = c - 1;
                float v = 0.f;
                if ((unsigned)gy < 64u && (unsigned)gx < 64u)
                    v = in[((b * CIN + cc * 8 + ci) * 64 + gy) * 64 + gx];
                s_a[ci][r][c] = v;
            }
        }
        __syncthreads();
        for (int ci = 0; ci < 8; ++ci) {
            float p[4][4];
#pragma unroll
            for (int rr = 0; rr < 4; ++rr)
#pragma unroll
                for (int s = 0; s < 4; ++s)
                    p[rr][s] = s_a[ci][2 * ty + rr][2 * tx + s];
            const float* wp = &w[(oc0 * CIN + cc * 8 + ci) * 9];
#pragma unroll
            for (int ky = 0; ky < 3; ++ky)
#pragma unroll
                for (int kx = 0; kx < 3; ++kx) {
#pragma unroll
                    for (int co = 0; co < 8; ++co) {
                        float wv = wp[co * CIN * 9 + ky * 3 + kx];
#pragma unroll
                        for (int jr = 0; jr < 2; ++jr)
#pragma unroll
                            for (int jc = 0; jc < 2; ++jc)
                                acc[jr * 2 + jc][co] += p[jr + ky][jc + kx] * wv;
                    }
                }
        }
    }
#pragma unroll
    for (int co = 0; co < 8; ++co) {
        int oc = oc0 + co;
        float bv = HASBIAS ? bias[oc] : 0.f;
#pragma unroll
        for (int jr = 0; jr < 2; ++jr)
#pragma unroll
            for (int jc = 0; jc < 2; ++jc) {
                float v = acc[jr * 2 + jc][co] + bv;
                if (RELU) v = frelu(v);
                out[((b * COUT + oc) * 64 + y0 + 2 * ty + jr) * 64 + 2 * tx + jc] = v;
            }
    }
}

// ---------- residual 1x1: x += relu(conv1x1(t)), 32->128 ------------------------
__global__ __launch_bounds__(256) void k_res1x1(const float* __restrict__ tin,
    const float* __restrict__ w, float* __restrict__ xbuf)
{
    int gid = blockIdx.x * 256 + threadIdx.x;   // 16 * 8 * 4096
    int px = gid & 4095;
    int cg = (gid >> 12) & 7;
    int b = gid >> 15;
    float acc[16];
#pragma unroll
    for (int i = 0; i < 16; ++i) acc[i] = 0.f;
#pragma unroll
    for (int ci = 0; ci < 32; ++ci) {
        float v = tin[(b * 32 + ci) * 4096 + px];
#pragma unroll
        for (int co = 0; co < 16; ++co)
            acc[co] += v * w[(cg * 16 + co) * 32 + ci];
    }
#pragma unroll
    for (int co = 0; co < 16; ++co) {
        int o = (b * 128 + cg * 16 + co) * 4096 + px;
        xbuf[o] = xbuf[o] + frelu(acc[co]);
    }
}

// ---------- VQ pass 1: direct (z-e)^2, exact reference semantics, 4 e-slices ----
__global__ __launch_bounds__(256) void k_vq1(const float* __restrict__ z,
    const float* __restrict__ emb, float* __restrict__ distb, int* __restrict__ idxb)
{
    const int gid = blockIdx.x * 256 + threadIdx.x;   // 262144
    const int px = gid & 65535, slice = gid >> 16;
    const int b = px >> 12, h = (px >> 6) & 63, wq = px & 63;
    float zr[64];
#pragma unroll
    for (int d = 0; d < 64; ++d)
        zr[d] = z[((b * 64 + d) * 64 + h) * 64 + wq];

    float best = 3.4e38f; int bi = 0;
    const int e0 = slice * 128;
#pragma unroll 1
    for (int e = 0; e < 128; ++e) {
        const float* er = emb + (e0 + e) * 64;        // block-uniform -> s_load
        float dist = 0.f;
#pragma unroll
        for (int d = 0; d < 64; ++d) {
            float df = zr[d] - er[d];
            dist += df * df;                           // single chain, ascending d
        }
        if (dist < best) { best = dist; bi = e0 + e; } // strict < -> first min
    }
    distb[gid] = best;
    idxb[gid] = bi;
}

// ---------- VQ pass 2: merge slices (ascending -> first-min tiebreak), loss part -
__global__ __launch_bounds__(256) void k_vq2(const float* __restrict__ distb,
    const int* __restrict__ idxb, int* __restrict__ idx, float* __restrict__ part)
{
    const int t = threadIdx.x;
    const int px = blockIdx.x * 256 + t;
    float best = distb[px]; int bi = idxb[px];
#pragma unroll
    for (int s2 = 1; s2 < 4; ++s2) {
        float d = distb[s2 * 65536 + px];
        int i2 = idxb[s2 * 65536 + px];
        if (d < best) { best = d; bi = i2; }
    }
    idx[px] = bi;
    float s = best;
#pragma unroll
    for (int off = 32; off > 0; off >>= 1) s += __shfl_down(s, off, 64);
    __shared__ float sw[4];
    if ((t & 63) == 0) sw[t >> 6] = s;
    __syncthreads();
    if (t == 0) part[blockIdx.x] = sw[0] + sw[1] + sw[2] + sw[3];
}

// ---------- build quantized NCHW via LDS transpose ------------------------------
__global__ __launch_bounds__(256) void k_qbuild(const int* __restrict__ idx,
    const float* __restrict__ emb, float* __restrict__ q)
{
    const int t = threadIdx.x;
    const int bh = blockIdx.x;            // b*64 + h
    const int b = bh >> 6, h = bh & 63;
    __shared__ int s_idx[64];
    __shared__ float s_e[64 * 65];
    if (t < 64) s_idx[t] = idx[(b << 12) | (h << 6) | t];
    __syncthreads();
#pragma unroll
    for (int k = 0; k < 16; ++k) {
        int i = t + (k << 8);
        int wq = i >> 6, d = i & 63;
        s_e[wq * 65 + d] = emb[s_idx[wq] * 64 + d];   // coalesced emb rows
    }
    __syncthreads();
#pragma unroll
    for (int k = 0; k < 16; ++k) {
        int i = t + (k << 8);
        int d = i >> 6, wq = i & 63;
        q[((b * 64 + d) * 64 + h) * 64 + wq] = s_e[wq * 65 + d];
    }
}

__global__ __launch_bounds__(256) void k_loss(const float* __restrict__ part,
    float* __restrict__ out)
{
    int t = threadIdx.x;
    float s = part[t];
#pragma unroll
    for (int off = 32; off > 0; off >>= 1) s += __shfl_down(s, off, 64);
    __shared__ float sw[4];
    if ((t & 63) == 0) sw[t >> 6] = s;
    __syncthreads();
    if (t == 0) out[3145728] = 1.25f * (sw[0] + sw[1] + sw[2] + sw[3]) / 4194304.0f;
}

// ---------- ConvTranspose2d k4 s2 p1 + bias + relu, as 4 parity sub-convs -------
template<int CIN, int COUT, int COT, int IW>
__global__ __launch_bounds__(256) void k_convTP(const float* __restrict__ in,
    const float* __restrict__ w, const float* __restrict__ bias, float* __restrict__ out)
{
    constexpr int NTX = IW / 4;           // threads along x
    constexpr int NTY = 256 / NTX;        // rows per tile
    constexpr int NCG = COUT / COT;
    constexpr int STR = IW + 8;           // LDS row stride (mult of 4)
    const int t = threadIdx.x;
    const int ty = t / NTX, tx = t % NTX;
    const int rt = blockIdx.x;            // IW/NTY row tiles
    const int bcg = blockIdx.y;
    const int b = bcg / NCG, cg = bcg % NCG;
    const int par = blockIdx.z;
    const int py = par >> 1, px = par & 1;
    const int y0 = rt * NTY;
    const int pr0 = y0 - 1 + py;          // first staged global row
    const int oc0 = cg * COT;

    __shared__ __align__(16) float s_a[8][NTY + 1][STR];

    float acc[4][COT];
#pragma unroll
    for (int j = 0; j < 4; ++j)
#pragma unroll
        for (int c = 0; c < COT; ++c) acc[j][c] = 0.f;

    const int kyA = py ? 0 : 1, kyB = py ? 2 : 3;
    const int kxA = px ? 0 : 1, kxB = px ? 2 : 3;

#pragma unroll 1
    for (int cc = 0; cc < CIN / 8; ++cc) {
        __syncthreads();
        for (int ci = 0; ci < 8; ++ci) {
            for (int j = t; j < (NTY + 1) * (IW + 1); j += 256) {
                int r = j / (IW + 1), c = j % (IW + 1);
                int gy = pr0 + r, gx = c - 1 + px;
                float v = 0.f;
                if ((unsigned)gy < (unsigned)IW && (unsigned)gx < (unsigned)IW)
                    v = in[((b * CIN + cc * 8 + ci) * IW + gy) * IW + gx];
                s_a[ci][r][c] = v;
            }
        }
        __syncthreads();
        for (int ci = 0; ci < 8; ++ci) {
            float p0[5], p1[5];
            {
                const float* r0 = &s_a[ci][ty][4 * tx];
                const float* r1 = &s_a[ci][ty + 1][4 * tx];
                float4 m0 = *reinterpret_cast<const float4*>(r0);
                float4 m1 = *reinterpret_cast<const float4*>(r1);
                p0[0] = m0.x; p0[1] = m0.y; p0[2] = m0.z; p0[3] = m0.w; p0[4] = r0[4];
                p1[0] = m1.x; p1[1] = m1.y; p1[2] = m1.z; p1[3] = m1.w; p1[4] = r1[4];
            }
            const int wbase = ((cc * 8 + ci) * COUT + oc0) * 16;
#pragma unroll
            for (int kyi = 0; kyi < 2; ++kyi) {
                const int ky = kyi ? kyB : kyA;
                const float* pr = kyi ? p0 : p1;
#pragma unroll
                for (int kxi = 0; kxi < 2; ++kxi) {
                    const int kx = kxi ? kxB : kxA;
                    const int cs = 1 - kxi;
#pragma unroll
                    for (int co = 0; co < COT; ++co) {
                        float wv = w[wbase + co * 16 + ky * 4 + kx];
#pragma unroll
                        for (int j = 0; j < 4; ++j)
                            acc[j][co] += pr[j + cs] * wv;
                    }
                }
            }
        }
    }
    const int oy = 2 * (y0 + ty) + py;
#pragma unroll
    for (int co = 0; co < COT; ++co) {
        int oc = oc0 + co;
        float bv = bias[oc];
#pragma unroll
        for (int j = 0; j < 4; ++j) {
            int ox = 8 * tx + 2 * j + px;
            out[((b * COUT + oc) * (2 * IW) + oy) * (2 * IW) + ox] =
                frelu(acc[j][co] + bv);
        }
    }
}

extern "C" void kernel_launch(void* const* d_in, const int* in_sizes, int n_in,
                              void* d_out, int out_size, void* d_ws, size_t ws_size,
                              hipStream_t stream)
{
    (void)in_sizes; (void)n_in; (void)out_size; (void)ws_size;
    const float* x    = (const float*)d_in[0];
    const float* emb  = (const float*)d_in[1];
    const float* ew1  = (const float*)d_in[2];
    const float* eb1  = (const float*)d_in[3];
    const float* ew2  = (const float*)d_in[4];
    const float* eb2  = (const float*)d_in[5];
    const float* er1a = (const float*)d_in[6];
    const float* er1b = (const float*)d_in[7];
    const float* er2a = (const float*)d_in[8];
    const float* er2b = (const float*)d_in[9];
    const float* ew3w = (const float*)d_in[10];
    const float* eb3  = (const float*)d_in[11];
    const float* dw1  = (const float*)d_in[12];
    const float* db1  = (const float*)d_in[13];
    const float* dr1a = (const float*)d_in[14];
    const float* dr1b = (const float*)d_in[15];
    const float* dr2a = (const float*)d_in[16];
    const float* dr2b = (const float*)d_in[17];
    const float* dtw1 = (const float*)d_in[18];
    const float* dtb1 = (const float*)d_in[19];
    const float* dtw2 = (const float*)d_in[20];
    const float* dtb2 = (const float*)d_in[21];
    float* out = (float*)d_out;
    float* ws  = (float*)d_ws;

    float* A    = ws;                          // [16,64,128,128] h1; later convT1 out
    float* Bf   = ws + 16777216;               // [16,128,64,64]
    float* T    = ws;                          // [16,32,64,64]   (h1 dead after ew2)
    float* Z    = ws + 2097152;                // [16,64,64,64]
    float* Q    = ws + 6291456;                // [16,64,64,64]
    int*   IDX  = (int*)(ws + 10485760);       // 65536
    float* PART = ws + 10551296;               // 256
    float* DISTB= ws + 10552064;               // 4*65536
    int*   IDXB = (int*)(ws + 10814208);       // 4*65536

    k_ew1<<<dim3(64, 16), 256, 0, stream>>>(x, ew1, eb1, A);
    k_ew2<<<dim3(4, 256), 256, 0, stream>>>(A, ew2, eb2, Bf);
    k_gconvQ22<128, 32, true, false><<<dim3(4, 64), 256, 0, stream>>>(Bf, er1a, nullptr, T);
    k_res1x1<<<2048, 256, 0, stream>>>(T, er1b, Bf);
    k_gconvQ22<128, 32, true, false><<<dim3(4, 64), 256, 0, stream>>>(Bf, er2a, nullptr, T);
    k_res1x1<<<2048, 256, 0, stream>>>(T, er2b, Bf);
    k_gconvW4<128, 64, false, true><<<dim3(4, 128), 256, 0, stream>>>(Bf, ew3w, eb3, Z);
    k_vq1<<<1024, 256, 0, stream>>>(Z, emb, DISTB, IDXB);
    k_vq2<<<256, 256, 0, stream>>>(DISTB, IDXB, IDX, PART);
    k_loss<<<1, 256, 0, stream>>>(PART, out);
    k_qbuild<<<1024, 256, 0, stream>>>(IDX, emb, Q);
    k_gconvW4<64, 128, false, true><<<dim3(4, 256), 256, 0, stream>>>(Q, dw1, db1, Bf);
    k_gconvQ22<128, 32, true, false><<<dim3(4, 64), 256, 0, stream>>>(Bf, dr1a, nullptr, T);
    k_res1x1<<<2048, 256, 0, stream>>>(T, dr1b, Bf);
    k_gconvQ22<128, 32, true, false><<<dim3(4, 64), 256, 0, stream>>>(Bf, dr2a, nullptr, T);
    k_res1x1<<<2048, 256, 0, stream>>>(T, dr2b, Bf);
    k_convTP<128, 64, 8, 64><<<dim3(4, 128, 4), 256, 0, stream>>>(Bf, dtw1, dtb1, A);
    k_convTP<64, 3, 3, 128><<<dim3(16, 16, 4), 256, 0, stream>>>(A, dtw2, dtb2, out);
}

// Round 8
// 3439.490 us; speedup vs baseline: 2.3481x; 1.1309x over previous
//
#include <hip/hip_runtime.h>

static __device__ __forceinline__ float frelu(float v) { return v > 0.f ? v : 0.f; }

// ---------- encoder conv1: 4x4 s2 p1, 3->64, bias+relu, 256^2 -> 128^2 ----------
__global__ __launch_bounds__(256) void k_ew1(const float* __restrict__ x,
    const float* __restrict__ w, const float* __restrict__ bias, float* __restrict__ out)
{
    const int t = threadIdx.x;
    const int tile = blockIdx.x;          // 64 tiles (8x8) of 16x16 over 128x128
    const int b = blockIdx.y;
    const int oy0 = (tile >> 3) << 4, ox0 = (tile & 7) << 4;
    const int tx = t & 15, ty = t >> 4;
    const int iy0 = 2 * oy0 - 1, ix0 = 2 * ox0 - 1;

    __shared__ float s_in[3 * 34 * 35];
    for (int i = t; i < 3 * 1156; i += 256) {
        int ci = i / 1156, rem = i % 1156, r = rem / 34, c = rem % 34;
        int gy = iy0 + r, gx = ix0 + c;
        float v = 0.f;
        if ((unsigned)gy < 256u && (unsigned)gx < 256u)
            v = x[((b * 3 + ci) * 256 + gy) * 256 + gx];
        s_in[(ci * 34 + r) * 35 + c] = v;
    }
    __syncthreads();

    float acc[64];
#pragma unroll
    for (int i = 0; i < 64; ++i) acc[i] = 0.f;
#pragma unroll
    for (int ci = 0; ci < 3; ++ci) {
        float v[16];
#pragma unroll
        for (int ky = 0; ky < 4; ++ky)
#pragma unroll
            for (int kx = 0; kx < 4; ++kx)
                v[ky * 4 + kx] = s_in[(ci * 34 + 2 * ty + ky) * 35 + 2 * tx + kx];
#pragma unroll
        for (int co = 0; co < 64; ++co)
#pragma unroll
            for (int k = 0; k < 16; ++k)
                acc[co] += v[k] * w[(co * 3 + ci) * 16 + k];
    }
#pragma unroll
    for (int co = 0; co < 64; ++co)
        out[((b * 64 + co) * 128 + oy0 + ty) * 128 + ox0 + tx] = frelu(acc[co] + bias[co]);
}

// ---------- encoder conv2: 4x4 s2 p1, 64->128, float2-parity staging, 4px x 16co -
// Per-acc summation order: channel asc (cc*2+ci), then ky asc, kx asc -> bitwise
// identical to the round-7 passing ew2 (z and VQ indices unchanged).
__global__ __launch_bounds__(256) void k_ew2(const float* __restrict__ in,
    const float* __restrict__ w, const float* __restrict__ bias, float* __restrict__ out)
{
    const int t = threadIdx.x;
    const int ty = t >> 4, tx = t & 15;   // 16 x 16 threads; thread = 1x4 out px
    const int rt = blockIdx.x;            // 4 row tiles of 16 rows over 64x64 out
    const int bcg = blockIdx.y;           // b*8 + cg  (16 co each)
    const int b = bcg >> 3, cg = bcg & 7;
    const int y0 = rt << 4;
    const int oc0 = cg << 4;

    // parity planes: [ci2][pr*2+pc][17][68]; plane(pr,pc) row r col c holds
    // input (2*(y0+r)-pr, 2*c-pc).  cols 0..64 used, stride 68 (16B-aligned rows).
    __shared__ __align__(16) float s_a[2][4][17][68];

    // pad columns never touched by staging: plane(pc=0) col 64 (gx=128),
    // plane(pc=1) col 0 (gx=-1) -> zero once.
    for (int i = t; i < 68; i += 256) {   // 2ci * 2pr * 17r
        int ci = i / 34, rem = i % 34, pr = rem / 17, r = rem % 17;
        s_a[ci][pr * 2 + 0][r][64] = 0.f;
        s_a[ci][pr * 2 + 1][r][0]  = 0.f;
    }

    float acc[4][16];
#pragma unroll
    for (int j = 0; j < 4; ++j)
#pragma unroll
        for (int c = 0; c < 16; ++c) acc[j][c] = 0.f;

#pragma unroll 1
    for (int cc = 0; cc < 32; ++cc) {     // 2 input channels per chunk
        __syncthreads();
#pragma unroll
        for (int ci = 0; ci < 2; ++ci) {
            const float* src = in + (size_t)((b * 64 + cc * 2 + ci) * 128) * 128;
            // 34 input rows (gy = 2*y0-1 .. 2*y0+32) x 64 float2 per row.
            // ir even -> gy odd -> pr=1; ir odd -> pr=0.  r = ir>>1 both ways.
            for (int j = t; j < 2176; j += 256) {
                int ir = j >> 6, c = j & 63;
                int gy = 2 * y0 - 1 + ir;
                int pr = 1 - (ir & 1), r = ir >> 1;
                float vx = 0.f, vy = 0.f;
                if ((unsigned)gy < 128u) {
                    float2 v = *reinterpret_cast<const float2*>(src + gy * 128 + 2 * c);
                    vx = v.x; vy = v.y;
                }
                s_a[ci][pr * 2 + 0][r][c] = vx;       // input (gy, 2c)
                s_a[ci][pr * 2 + 1][r][c + 1] = vy;   // input (gy, 2c+1)
            }
        }
        __syncthreads();
#pragma unroll
        for (int ci = 0; ci < 2; ++ci) {
            const float* wp = &w[(oc0 * 64 + cc * 2 + ci) * 16];
#pragma unroll
            for (int ky = 0; ky < 4; ++ky) {
                const int pr = 1 - (ky & 1);      // ky 0,2 -> odd input row plane
                const int rr = ky >> 1;           // ky 0,1 -> row ty; 2,3 -> ty+1
                float pv[2][5];
#pragma unroll
                for (int pc = 0; pc < 2; ++pc) {
                    const float* rp = &s_a[ci][pr * 2 + pc][ty + rr][4 * tx];
                    float4 m = *reinterpret_cast<const float4*>(rp);
                    pv[pc][0] = m.x; pv[pc][1] = m.y; pv[pc][2] = m.z; pv[pc][3] = m.w;
                    pv[pc][4] = rp[4];
                }
#pragma unroll
                for (int kx = 0; kx < 4; ++kx) {
                    const int pc = 1 - (kx & 1);
                    const int cs = kx >> 1;
#pragma unroll
                    for (int co = 0; co < 16; ++co) {
                        float wv = wp[co * 1024 + ky * 4 + kx];
#pragma unroll
                        for (int j = 0; j < 4; ++j)
                            acc[j][co] += pv[pc][j + cs] * wv;
                    }
                }
            }
        }
    }
#pragma unroll
    for (int co = 0; co < 16; ++co) {
        int oc = oc0 + co;
        float bv = bias[oc];
#pragma unroll
        for (int j = 0; j < 4; ++j)
            out[((b * 128 + oc) * 64 + y0 + ty) * 64 + 4 * tx + j] = frelu(acc[j][co] + bv);
    }
}

// ---------- 3x3 s1 p1 conv at 64x64, thread = 1x4 px, 8 co (weight reuse 4x) ----
template<int CIN, int COUT, bool RELU, bool HASBIAS>
__global__ __launch_bounds__(256) void k_gconvW4(const float* __restrict__ in,
    const float* __restrict__ w, const float* __restrict__ bias, float* __restrict__ out)
{
    constexpr int NCG = COUT / 8;
    const int t = threadIdx.x;
    const int ty = t >> 4, tx = t & 15;   // 16 x 16
    const int rt = blockIdx.x;            // 4 row-tiles of 16 rows
    const int bcg = blockIdx.y;
    const int b = bcg / NCG, cg = bcg % NCG;
    const int y0 = rt << 4;
    const int oc0 = cg << 3;

    __shared__ __align__(16) float s_a[8][18][72];  // global col gc -> L = gc+4

    float acc[4][8];
#pragma unroll
    for (int j = 0; j < 4; ++j)
#pragma unroll
        for (int c = 0; c < 8; ++c) acc[j][c] = 0.f;

#pragma unroll 1
    for (int cc = 0; cc < CIN / 8; ++cc) {
        __syncthreads();
        for (int ci = 0; ci < 8; ++ci) {
            for (int j = t; j < 18 * 66; j += 256) {
                int r = j / 66, c = j % 66;
                int gy = y0 - 1 + r, gx = c - 1;
                float v = 0.f;
                if ((unsigned)gy < 64u && (unsigned)gx < 64u)
                    v = in[((b * CIN + cc * 8 + ci) * 64 + gy) * 64 + gx];
                s_a[ci][r][c + 3] = v;
            }
        }
        __syncthreads();
        for (int ci = 0; ci < 8; ++ci) {
            float p[3][6];
#pragma unroll
            for (int rr = 0; rr < 3; ++rr) {
                const float* rowp = &s_a[ci][ty + rr][4 * tx + 3];
                p[rr][0] = rowp[0];
                float4 m = *reinterpret_cast<const float4*>(rowp + 1);
                p[rr][1] = m.x; p[rr][2] = m.y; p[rr][3] = m.z; p[rr][4] = m.w;
                p[rr][5] = rowp[5];
            }
            const float* wp = &w[(oc0 * CIN + cc * 8 + ci) * 9];
#pragma unroll
            for (int ky = 0; ky < 3; ++ky)
#pragma unroll
                for (int kx = 0; kx < 3; ++kx) {
#pragma unroll
                    for (int co = 0; co < 8; ++co) {
                        float wv = wp[co * CIN * 9 + ky * 3 + kx];
#pragma unroll
                        for (int j = 0; j < 4; ++j)
                            acc[j][co] += p[ky][j + kx] * wv;
                    }
                }
        }
    }
#pragma unroll
    for (int co = 0; co < 8; ++co) {
        int oc = oc0 + co;
        float bv = HASBIAS ? bias[oc] : 0.f;
#pragma unroll
        for (int j = 0; j < 4; ++j) {
            float v = acc[j][co] + bv;
            if (RELU) v = frelu(v);
            out[((b * COUT + oc) * 64 + y0 + ty) * 64 + 4 * tx + j] = v;
        }
    }
}

// ---------- 3x3 s1 p1 conv at 64x64, thread = 2x2 px, 8 co (for COUT=32) --------
template<int CIN, int COUT, bool RELU, bool HASBIAS>
__global__ __launch_bounds__(256) void k_gconvQ22(const float* __restrict__ in,
    const float* __restrict__ w, const float* __restrict__ bias, float* __restrict__ out)
{
    constexpr int NCG = COUT / 8;
    const int t = threadIdx.x;
    const int ty = t >> 5, tx = t & 31;   // 8 x 32 -> 2x2 px each => 16 x 64 tile
    const int rt = blockIdx.x;            // 4 row-tiles
    const int bcg = blockIdx.y;
    const int b = bcg / NCG, cg = bcg % NCG;
    const int y0 = rt << 4;
    const int oc0 = cg << 3;

    __shared__ __align__(16) float s_a[8][18][68];

    float acc[4][8];
#pragma unroll
    for (int j = 0; j < 4; ++j)
#pragma unroll
        for (int c = 0; c < 8; ++c) acc[j][c] = 0.f;

#pragma unroll 1
    for (int cc = 0; cc < CIN / 8; ++cc) {
        __syncthreads();
        for (int ci = 0; ci < 8; ++ci) {
            for (int j = t; j < 18 * 66; j += 256) {
                int r = j / 66, c = j % 66;
                int gy = y0 - 1 + r, gx = c - 1;
                float v = 0.f;
                if ((unsigned)gy < 64u && (unsigned)gx < 64u)
                    v = in[((b * CIN + cc * 8 + ci) * 64 + gy) * 64 + gx];
                s_a[ci][r][c] = v;
            }
        }
        __syncthreads();
        for (int ci = 0; ci < 8; ++ci) {
            float p[4][4];
#pragma unroll
            for (int rr = 0; rr < 4; ++rr)
#pragma unroll
                for (int s = 0; s < 4; ++s)
                    p[rr][s] = s_a[ci][2 * ty + rr][2 * tx + s];
            const float* wp = &w[(oc0 * CIN + cc * 8 + ci) * 9];
#pragma unroll
            for (int ky = 0; ky < 3; ++ky)
#pragma unroll
                for (int kx = 0; kx < 3; ++kx) {
#pragma unroll
                    for (int co = 0; co < 8; ++co) {
                        float wv = wp[co * CIN * 9 + ky * 3 + kx];
#pragma unroll
                        for (int jr = 0; jr < 2; ++jr)
#pragma unroll
                            for (int jc = 0; jc < 2; ++jc)
                                acc[jr * 2 + jc][co] += p[jr + ky][jc + kx] * wv;
                    }
                }
        }
    }
#pragma unroll
    for (int co = 0; co < 8; ++co) {
        int oc = oc0 + co;
        float bv = HASBIAS ? bias[oc] : 0.f;
#pragma unroll
        for (int jr = 0; jr < 2; ++jr)
#pragma unroll
            for (int jc = 0; jc < 2; ++jc) {
                float v = acc[jr * 2 + jc][co] + bv;
                if (RELU) v = frelu(v);
                out[((b * COUT + oc) * 64 + y0 + 2 * ty + jr) * 64 + 2 * tx + jc] = v;
            }
    }
}

// ---------- residual 1x1: x += relu(conv1x1(t)), 32->128 ------------------------
__global__ __launch_bounds__(256) void k_res1x1(const float* __restrict__ tin,
    const float* __restrict__ w, float* __restrict__ xbuf)
{
    int gid = blockIdx.x * 256 + threadIdx.x;   // 16 * 8 * 4096
    int px = gid & 4095;
    int cg = (gid >> 12) & 7;
    int b = gid >> 15;
    float acc[16];
#pragma unroll
    for (int i = 0; i < 16; ++i) acc[i] = 0.f;
#pragma unroll
    for (int ci = 0; ci < 32; ++ci) {
        float v = tin[(b * 32 + ci) * 4096 + px];
#pragma unroll
        for (int co = 0; co < 16; ++co)
            acc[co] += v * w[(cg * 16 + co) * 32 + ci];
    }
#pragma unroll
    for (int co = 0; co < 16; ++co) {
        int o = (b * 128 + cg * 16 + co) * 4096 + px;
        xbuf[o] = xbuf[o] + frelu(acc[co]);
    }
}

// ---------- VQ pass 1: direct (z-e)^2, exact reference semantics, 4 e-slices ----
__global__ __launch_bounds__(256) void k_vq1(const float* __restrict__ z,
    const float* __restrict__ emb, float* __restrict__ distb, int* __restrict__ idxb)
{
    const int gid = blockIdx.x * 256 + threadIdx.x;   // 262144
    const int px = gid & 65535, slice = gid >> 16;
    const int b = px >> 12, h = (px >> 6) & 63, wq = px & 63;
    float zr[64];
#pragma unroll
    for (int d = 0; d < 64; ++d)
        zr[d] = z[((b * 64 + d) * 64 + h) * 64 + wq];

    float best = 3.4e38f; int bi = 0;
    const int e0 = slice * 128;
#pragma unroll 1
    for (int e = 0; e < 128; ++e) {
        const float* er = emb + (e0 + e) * 64;        // block-uniform -> s_load
        float dist = 0.f;
#pragma unroll
        for (int d = 0; d < 64; ++d) {
            float df = zr[d] - er[d];
            dist += df * df;                           // single chain, ascending d
        }
        if (dist < best) { best = dist; bi = e0 + e; } // strict < -> first min
    }
    distb[gid] = best;
    idxb[gid] = bi;
}

// ---------- VQ pass 2: merge slices (ascending -> first-min tiebreak), loss part -
__global__ __launch_bounds__(256) void k_vq2(const float* __restrict__ distb,
    const int* __restrict__ idxb, int* __restrict__ idx, float* __restrict__ part)
{
    const int t = threadIdx.x;
    const int px = blockIdx.x * 256 + t;
    float best = distb[px]; int bi = idxb[px];
#pragma unroll
    for (int s2 = 1; s2 < 4; ++s2) {
        float d = distb[s2 * 65536 + px];
        int i2 = idxb[s2 * 65536 + px];
        if (d < best) { best = d; bi = i2; }
    }
    idx[px] = bi;
    float s = best;
#pragma unroll
    for (int off = 32; off > 0; off >>= 1) s += __shfl_down(s, off, 64);
    __shared__ float sw[4];
    if ((t & 63) == 0) sw[t >> 6] = s;
    __syncthreads();
    if (t == 0) part[blockIdx.x] = sw[0] + sw[1] + sw[2] + sw[3];
}

// ---------- build quantized NCHW via LDS transpose ------------------------------
__global__ __launch_bounds__(256) void k_qbuild(const int* __restrict__ idx,
    const float* __restrict__ emb, float* __restrict__ q)
{
    const int t = threadIdx.x;
    const int bh = blockIdx.x;            // b*64 + h
    const int b = bh >> 6, h = bh & 63;
    __shared__ int s_idx[64];
    __shared__ float s_e[64 * 65];
    if (t < 64) s_idx[t] = idx[(b << 12) | (h << 6) | t];
    __syncthreads();
#pragma unroll
    for (int k = 0; k < 16; ++k) {
        int i = t + (k << 8);
        int wq = i >> 6, d = i & 63;
        s_e[wq * 65 + d] = emb[s_idx[wq] * 64 + d];   // coalesced emb rows
    }
    __syncthreads();
#pragma unroll
    for (int k = 0; k < 16; ++k) {
        int i = t + (k << 8);
        int d = i >> 6, wq = i & 63;
        q[((b * 64 + d) * 64 + h) * 64 + wq] = s_e[wq * 65 + d];
    }
}

__global__ __launch_bounds__(256) void k_loss(const float* __restrict__ part,
    float* __restrict__ out)
{
    int t = threadIdx.x;
    float s = part[t];
#pragma unroll
    for (int off = 32; off > 0; off >>= 1) s += __shfl_down(s, off, 64);
    __shared__ float sw[4];
    if ((t & 63) == 0) sw[t >> 6] = s;
    __syncthreads();
    if (t == 0) out[3145728] = 1.25f * (sw[0] + sw[1] + sw[2] + sw[3]) / 4194304.0f;
}

// ---------- ConvTranspose2d k4 s2 p1 + bias + relu, as 4 parity sub-convs -------
template<int CIN, int COUT, int COT, int IW>
__global__ __launch_bounds__(256) void k_convTP(const float* __restrict__ in,
    const float* __restrict__ w, const float* __restrict__ bias, float* __restrict__ out)
{
    constexpr int NTX = IW / 4;           // threads along x
    constexpr int NTY = 256 / NTX;        // rows per tile
    constexpr int NCG = COUT / COT;
    constexpr int STR = IW + 8;           // LDS row stride (mult of 4)
    const int t = threadIdx.x;
    const int ty = t / NTX, tx = t % NTX;
    const int rt = blockIdx.x;            // IW/NTY row tiles
    const int bcg = blockIdx.y;
    const int b = bcg / NCG, cg = bcg % NCG;
    const int par = blockIdx.z;
    const int py = par >> 1, px = par & 1;
    const int y0 = rt * NTY;
    const int pr0 = y0 - 1 + py;          // first staged global row
    const int oc0 = cg * COT;

    __shared__ __align__(16) float s_a[8][NTY + 1][STR];

    float acc[4][COT];
#pragma unroll
    for (int j = 0; j < 4; ++j)
#pragma unroll
        for (int c = 0; c < COT; ++c) acc[j][c] = 0.f;

    const int kyA = py ? 0 : 1, kyB = py ? 2 : 3;
    const int kxA = px ? 0 : 1, kxB = px ? 2 : 3;

#pragma unroll 1
    for (int cc = 0; cc < CIN / 8; ++cc) {
        __syncthreads();
        for (int ci = 0; ci < 8; ++ci) {
            for (int j = t; j < (NTY + 1) * (IW + 1); j += 256) {
                int r = j / (IW + 1), c = j % (IW + 1);
                int gy = pr0 + r, gx = c - 1 + px;
                float v = 0.f;
                if ((unsigned)gy < (unsigned)IW && (unsigned)gx < (unsigned)IW)
                    v = in[((b * CIN + cc * 8 + ci) * IW + gy) * IW + gx];
                s_a[ci][r][c] = v;
            }
        }
        __syncthreads();
        for (int ci = 0; ci < 8; ++ci) {
            float p0[5], p1[5];
            {
                const float* r0 = &s_a[ci][ty][4 * tx];
                const float* r1 = &s_a[ci][ty + 1][4 * tx];
                float4 m0 = *reinterpret_cast<const float4*>(r0);
                float4 m1 = *reinterpret_cast<const float4*>(r1);
                p0[0] = m0.x; p0[1] = m0.y; p0[2] = m0.z; p0[3] = m0.w; p0[4] = r0[4];
                p1[0] = m1.x; p1[1] = m1.y; p1[2] = m1.z; p1[3] = m1.w; p1[4] = r1[4];
            }
            const int wbase = ((cc * 8 + ci) * COUT + oc0) * 16;
#pragma unroll
            for (int kyi = 0; kyi < 2; ++kyi) {
                const int ky = kyi ? kyB : kyA;
                const float* pr = kyi ? p0 : p1;
#pragma unroll
                for (int kxi = 0; kxi < 2; ++kxi) {
                    const int kx = kxi ? kxB : kxA;
                    const int cs = 1 - kxi;
#pragma unroll
                    for (int co = 0; co < COT; ++co) {
                        float wv = w[wbase + co * 16 + ky * 4 + kx];
#pragma unroll
                        for (int j = 0; j < 4; ++j)
                            acc[j][co] += pr[j + cs] * wv;
                    }
                }
            }
        }
    }
    const int oy = 2 * (y0 + ty) + py;
#pragma unroll
    for (int co = 0; co < COT; ++co) {
        int oc = oc0 + co;
        float bv = bias[oc];
#pragma unroll
        for (int j = 0; j < 4; ++j) {
            int ox = 8 * tx + 2 * j + px;
            out[((b * COUT + oc) * (2 * IW) + oy) * (2 * IW) + ox] =
                frelu(acc[j][co] + bv);
        }
    }
}

extern "C" void kernel_launch(void* const* d_in, const int* in_sizes, int n_in,
                              void* d_out, int out_size, void* d_ws, size_t ws_size,
                              hipStream_t stream)
{
    (void)in_sizes; (void)n_in; (void)out_size; (void)ws_size;
    const float* x    = (const float*)d_in[0];
    const float* emb  = (const float*)d_in[1];
    const float* ew1  = (const float*)d_in[2];
    const float* eb1  = (const float*)d_in[3];
    const float* ew2  = (const float*)d_in[4];
    const float* eb2  = (const float*)d_in[5];
    const float* er1a = (const float*)d_in[6];
    const float* er1b = (const float*)d_in[7];
    const float* er2a = (const float*)d_in[8];
    const float* er2b = (const float*)d_in[9];
    const float* ew3w = (const float*)d_in[10];
    const float* eb3  = (const float*)d_in[11];
    const float* dw1  = (const float*)d_in[12];
    const float* db1  = (const float*)d_in[13];
    const float* dr1a = (const float*)d_in[14];
    const float* dr1b = (const float*)d_in[15];
    const float* dr2a = (const float*)d_in[16];
    const float* dr2b = (const float*)d_in[17];
    const float* dtw1 = (const float*)d_in[18];
    const float* dtb1 = (const float*)d_in[19];
    const float* dtw2 = (const float*)d_in[20];
    const float* dtb2 = (const float*)d_in[21];
    float* out = (float*)d_out;
    float* ws  = (float*)d_ws;

    float* A    = ws;                          // [16,64,128,128] h1; later convT1 out
    float* Bf   = ws + 16777216;               // [16,128,64,64]
    float* T    = ws;                          // [16,32,64,64]   (h1 dead after ew2)
    float* Z    = ws + 2097152;                // [16,64,64,64]
    float* Q    = ws + 6291456;                // [16,64,64,64]
    int*   IDX  = (int*)(ws + 10485760);       // 65536
    float* PART = ws + 10551296;               // 256
    float* DISTB= ws + 10552064;               // 4*65536
    int*   IDXB = (int*)(ws + 10814208);       // 4*65536

    k_ew1<<<dim3(64, 16), 256, 0, stream>>>(x, ew1, eb1, A);
    k_ew2<<<dim3(4, 128), 256, 0, stream>>>(A, ew2, eb2, Bf);
    k_gconvQ22<128, 32, true, false><<<dim3(4, 64), 256, 0, stream>>>(Bf, er1a, nullptr, T);
    k_res1x1<<<2048, 256, 0, stream>>>(T, er1b, Bf);
    k_gconvQ22<128, 32, true, false><<<dim3(4, 64), 256, 0, stream>>>(Bf, er2a, nullptr, T);
    k_res1x1<<<2048, 256, 0, stream>>>(T, er2b, Bf);
    k_gconvW4<128, 64, false, true><<<dim3(4, 128), 256, 0, stream>>>(Bf, ew3w, eb3, Z);
    k_vq1<<<1024, 256, 0, stream>>>(Z, emb, DISTB, IDXB);
    k_vq2<<<256, 256, 0, stream>>>(DISTB, IDXB, IDX, PART);
    k_loss<<<1, 256, 0, stream>>>(PART, out);
    k_qbuild<<<1024, 256, 0, stream>>>(IDX, emb, Q);
    k_gconvW4<64, 128, false, true><<<dim3(4, 256), 256, 0, stream>>>(Q, dw1, db1, Bf);
    k_gconvQ22<128, 32, true, false><<<dim3(4, 64), 256, 0, stream>>>(Bf, dr1a, nullptr, T);
    k_res1x1<<<2048, 256, 0, stream>>>(T, dr1b, Bf);
    k_gconvQ22<128, 32, true, false><<<dim3(4, 64), 256, 0, stream>>>(Bf, dr2a, nullptr, T);
    k_res1x1<<<2048, 256, 0, stream>>>(T, dr2b, Bf);
    k_convTP<128, 64, 8, 64><<<dim3(4, 128, 4), 256, 0, stream>>>(Bf, dtw1, dtb1, A);
    k_convTP<64, 3, 3, 128><<<dim3(16, 16, 4), 256, 0, stream>>>(A, dtw2, dtb2, out);
}

// Round 9
// 2995.442 us; speedup vs baseline: 2.6962x; 1.1482x over previous
//
#include <hip/hip_runtime.h>

static __device__ __forceinline__ float frelu(float v) { return v > 0.f ? v : 0.f; }

// ---------- encoder conv1: 4x4 s2 p1, 3->64, bias+relu, 256^2 -> 128^2 ----------
__global__ __launch_bounds__(256) void k_ew1(const float* __restrict__ x,
    const float* __restrict__ w, const float* __restrict__ bias, float* __restrict__ out)
{
    const int t = threadIdx.x;
    const int tile = blockIdx.x;          // 64 tiles (8x8) of 16x16 over 128x128
    const int b = blockIdx.y;
    const int oy0 = (tile >> 3) << 4, ox0 = (tile & 7) << 4;
    const int tx = t & 15, ty = t >> 4;
    const int iy0 = 2 * oy0 - 1, ix0 = 2 * ox0 - 1;

    __shared__ float s_in[3 * 34 * 35];
    for (int i = t; i < 3 * 1156; i += 256) {
        int ci = i / 1156, rem = i % 1156, r = rem / 34, c = rem % 34;
        int gy = iy0 + r, gx = ix0 + c;
        float v = 0.f;
        if ((unsigned)gy < 256u && (unsigned)gx < 256u)
            v = x[((b * 3 + ci) * 256 + gy) * 256 + gx];
        s_in[(ci * 34 + r) * 35 + c] = v;
    }
    __syncthreads();

    float acc[64];
#pragma unroll
    for (int i = 0; i < 64; ++i) acc[i] = 0.f;
#pragma unroll
    for (int ci = 0; ci < 3; ++ci) {
        float v[16];
#pragma unroll
        for (int ky = 0; ky < 4; ++ky)
#pragma unroll
            for (int kx = 0; kx < 4; ++kx)
                v[ky * 4 + kx] = s_in[(ci * 34 + 2 * ty + ky) * 35 + 2 * tx + kx];
#pragma unroll
        for (int co = 0; co < 64; ++co)
#pragma unroll
            for (int k = 0; k < 16; ++k)
                acc[co] += v[k] * w[(co * 3 + ci) * 16 + k];
    }
#pragma unroll
    for (int co = 0; co < 64; ++co)
        out[((b * 64 + co) * 128 + oy0 + ty) * 128 + ox0 + tx] = frelu(acc[co] + bias[co]);
}

// ---------- encoder conv2: 4x4 s2 p1, 64->128, float2-parity staging, 4px x 16co -
// Per-acc summation order: channel asc (cc*2+ci), then ky asc, kx asc -> bitwise
// identical to the round-7/8 passing ew2 (z and VQ indices unchanged).
__global__ __launch_bounds__(256) void k_ew2(const float* __restrict__ in,
    const float* __restrict__ w, const float* __restrict__ bias, float* __restrict__ out)
{
    const int t = threadIdx.x;
    const int ty = t >> 4, tx = t & 15;   // 16 x 16 threads; thread = 1x4 out px
    const int rt = blockIdx.x;            // 4 row tiles of 16 rows over 64x64 out
    const int bcg = blockIdx.y;           // b*8 + cg  (16 co each)
    const int b = bcg >> 3, cg = bcg & 7;
    const int y0 = rt << 4;
    const int oc0 = cg << 4;

    __shared__ __align__(16) float s_a[2][4][17][68];

    for (int i = t; i < 68; i += 256) {   // 2ci * 2pr * 17r
        int ci = i / 34, rem = i % 34, pr = rem / 17, r = rem % 17;
        s_a[ci][pr * 2 + 0][r][64] = 0.f;
        s_a[ci][pr * 2 + 1][r][0]  = 0.f;
    }

    float acc[4][16];
#pragma unroll
    for (int j = 0; j < 4; ++j)
#pragma unroll
        for (int c = 0; c < 16; ++c) acc[j][c] = 0.f;

#pragma unroll 1
    for (int cc = 0; cc < 32; ++cc) {     // 2 input channels per chunk
        __syncthreads();
#pragma unroll
        for (int ci = 0; ci < 2; ++ci) {
            const float* src = in + (size_t)((b * 64 + cc * 2 + ci) * 128) * 128;
            for (int j = t; j < 2176; j += 256) {
                int ir = j >> 6, c = j & 63;
                int gy = 2 * y0 - 1 + ir;
                int pr = 1 - (ir & 1), r = ir >> 1;
                float vx = 0.f, vy = 0.f;
                if ((unsigned)gy < 128u) {
                    float2 v = *reinterpret_cast<const float2*>(src + gy * 128 + 2 * c);
                    vx = v.x; vy = v.y;
                }
                s_a[ci][pr * 2 + 0][r][c] = vx;
                s_a[ci][pr * 2 + 1][r][c + 1] = vy;
            }
        }
        __syncthreads();
#pragma unroll
        for (int ci = 0; ci < 2; ++ci) {
            const float* wp = &w[(oc0 * 64 + cc * 2 + ci) * 16];
#pragma unroll
            for (int ky = 0; ky < 4; ++ky) {
                const int pr = 1 - (ky & 1);
                const int rr = ky >> 1;
                float pv[2][5];
#pragma unroll
                for (int pc = 0; pc < 2; ++pc) {
                    const float* rp = &s_a[ci][pr * 2 + pc][ty + rr][4 * tx];
                    float4 m = *reinterpret_cast<const float4*>(rp);
                    pv[pc][0] = m.x; pv[pc][1] = m.y; pv[pc][2] = m.z; pv[pc][3] = m.w;
                    pv[pc][4] = rp[4];
                }
#pragma unroll
                for (int kx = 0; kx < 4; ++kx) {
                    const int pc = 1 - (kx & 1);
                    const int cs = kx >> 1;
#pragma unroll
                    for (int co = 0; co < 16; ++co) {
                        float wv = wp[co * 1024 + ky * 4 + kx];
#pragma unroll
                        for (int j = 0; j < 4; ++j)
                            acc[j][co] += pv[pc][j + cs] * wv;
                    }
                }
            }
        }
    }
#pragma unroll
    for (int co = 0; co < 16; ++co) {
        int oc = oc0 + co;
        float bv = bias[oc];
#pragma unroll
        for (int j = 0; j < 4; ++j)
            out[((b * 128 + oc) * 64 + y0 + ty) * 64 + 4 * tx + j] = frelu(acc[j][co] + bv);
    }
}

// ---------- 3x3 s1 p1 conv at 64x64, thread = 1x4 px, COT co -------------------
// Same values into same LDS slots as before; compute order unchanged per acc.
template<int CIN, int COUT, int COT, bool RELU, bool HASBIAS>
__global__ __launch_bounds__(256) void k_gconvW4(const float* __restrict__ in,
    const float* __restrict__ w, const float* __restrict__ bias, float* __restrict__ out)
{
    constexpr int NCG = COUT / COT;
    const int t = threadIdx.x;
    const int ty = t >> 4, tx = t & 15;   // 16 x 16
    const int rt = blockIdx.x;            // 4 row-tiles of 16 rows
    const int bcg = blockIdx.y;
    const int b = bcg / NCG, cg = bcg % NCG;
    const int y0 = rt << 4;
    const int oc0 = cg * COT;

    __shared__ __align__(16) float s_a[8][18][72];  // col(gx) = gx + 4

    // halo cols gx=-1 (col 3) and gx=64 (col 68) are always zero
    for (int i = t; i < 144; i += 256) {
        int ci = i / 18, r = i % 18;
        s_a[ci][r][3] = 0.f;
        s_a[ci][r][68] = 0.f;
    }

    float acc[4][COT];
#pragma unroll
    for (int j = 0; j < 4; ++j)
#pragma unroll
        for (int c = 0; c < COT; ++c) acc[j][c] = 0.f;

#pragma unroll 1
    for (int cc = 0; cc < CIN / 8; ++cc) {
        __syncthreads();
        for (int ci = 0; ci < 8; ++ci) {
            const float* src = in + (size_t)((b * CIN + cc * 8 + ci) * 64) * 64;
            for (int j = t; j < 18 * 64; j += 256) {
                int r = j >> 6, c = j & 63;
                int gy = y0 - 1 + r;
                float v = ((unsigned)gy < 64u) ? src[gy * 64 + c] : 0.f;
                s_a[ci][r][c + 4] = v;
            }
        }
        __syncthreads();
        for (int ci = 0; ci < 8; ++ci) {
            float p[3][6];
#pragma unroll
            for (int rr = 0; rr < 3; ++rr) {
                const float* rowp = &s_a[ci][ty + rr][4 * tx + 3];
                p[rr][0] = rowp[0];
                float4 m = *reinterpret_cast<const float4*>(rowp + 1);
                p[rr][1] = m.x; p[rr][2] = m.y; p[rr][3] = m.z; p[rr][4] = m.w;
                p[rr][5] = rowp[5];
            }
            const float* wp = &w[(oc0 * CIN + cc * 8 + ci) * 9];
#pragma unroll
            for (int ky = 0; ky < 3; ++ky)
#pragma unroll
                for (int kx = 0; kx < 3; ++kx) {
#pragma unroll
                    for (int co = 0; co < COT; ++co) {
                        float wv = wp[co * CIN * 9 + ky * 3 + kx];
#pragma unroll
                        for (int j = 0; j < 4; ++j)
                            acc[j][co] += p[ky][j + kx] * wv;
                    }
                }
        }
    }
#pragma unroll
    for (int co = 0; co < COT; ++co) {
        int oc = oc0 + co;
        float bv = HASBIAS ? bias[oc] : 0.f;
#pragma unroll
        for (int j = 0; j < 4; ++j) {
            float v = acc[j][co] + bv;
            if (RELU) v = frelu(v);
            out[((b * COUT + oc) * 64 + y0 + ty) * 64 + 4 * tx + j] = v;
        }
    }
}

// ---------- 3x3 s1 p1 conv at 64x64, thread = 2x2 px, 8 co (for COUT=32) --------
template<int CIN, int COUT, bool RELU, bool HASBIAS>
__global__ __launch_bounds__(256) void k_gconvQ22(const float* __restrict__ in,
    const float* __restrict__ w, const float* __restrict__ bias, float* __restrict__ out)
{
    constexpr int NCG = COUT / 8;
    const int t = threadIdx.x;
    const int ty = t >> 5, tx = t & 31;   // 8 x 32 -> 2x2 px each => 16 x 64 tile
    const int rt = blockIdx.x;            // 4 row-tiles
    const int bcg = blockIdx.y;
    const int b = bcg / NCG, cg = bcg % NCG;
    const int y0 = rt << 4;
    const int oc0 = cg << 3;

    __shared__ __align__(16) float s_a[8][18][68];  // col(gx) = gx + 1

    // halo cols gx=-1 (col 0) and gx=64 (col 65) are always zero
    for (int i = t; i < 144; i += 256) {
        int ci = i / 18, r = i % 18;
        s_a[ci][r][0] = 0.f;
        s_a[ci][r][65] = 0.f;
    }

    float acc[4][8];
#pragma unroll
    for (int j = 0; j < 4; ++j)
#pragma unroll
        for (int c = 0; c < 8; ++c) acc[j][c] = 0.f;

#pragma unroll 1
    for (int cc = 0; cc < CIN / 8; ++cc) {
        __syncthreads();
        for (int ci = 0; ci < 8; ++ci) {
            const float* src = in + (size_t)((b * CIN + cc * 8 + ci) * 64) * 64;
            for (int j = t; j < 18 * 64; j += 256) {
                int r = j >> 6, c = j & 63;
                int gy = y0 - 1 + r;
                float v = ((unsigned)gy < 64u) ? src[gy * 64 + c] : 0.f;
                s_a[ci][r][c + 1] = v;
            }
        }
        __syncthreads();
        for (int ci = 0; ci < 8; ++ci) {
            float p[4][4];
#pragma unroll
            for (int rr = 0; rr < 4; ++rr)
#pragma unroll
                for (int s = 0; s < 4; ++s)
                    p[rr][s] = s_a[ci][2 * ty + rr][2 * tx + s];
            const float* wp = &w[(oc0 * CIN + cc * 8 + ci) * 9];
#pragma unroll
            for (int ky = 0; ky < 3; ++ky)
#pragma unroll
                for (int kx = 0; kx < 3; ++kx) {
#pragma unroll
                    for (int co = 0; co < 8; ++co) {
                        float wv = wp[co * CIN * 9 + ky * 3 + kx];
#pragma unroll
                        for (int jr = 0; jr < 2; ++jr)
#pragma unroll
                            for (int jc = 0; jc < 2; ++jc)
                                acc[jr * 2 + jc][co] += p[jr + ky][jc + kx] * wv;
                    }
                }
        }
    }
#pragma unroll
    for (int co = 0; co < 8; ++co) {
        int oc = oc0 + co;
        float bv = HASBIAS ? bias[oc] : 0.f;
#pragma unroll
        for (int jr = 0; jr < 2; ++jr)
#pragma unroll
            for (int jc = 0; jc < 2; ++jc) {
                float v = acc[jr * 2 + jc][co] + bv;
                if (RELU) v = frelu(v);
                out[((b * COUT + oc) * 64 + y0 + 2 * ty + jr) * 64 + 2 * tx + jc] = v;
            }
    }
}

// ---------- residual 1x1: x += relu(conv1x1(t)), 32->128 ------------------------
__global__ __launch_bounds__(256) void k_res1x1(const float* __restrict__ tin,
    const float* __restrict__ w, float* __restrict__ xbuf)
{
    int gid = blockIdx.x * 256 + threadIdx.x;   // 16 * 8 * 4096
    int px = gid & 4095;
    int cg = (gid >> 12) & 7;
    int b = gid >> 15;
    float acc[16];
#pragma unroll
    for (int i = 0; i < 16; ++i) acc[i] = 0.f;
#pragma unroll
    for (int ci = 0; ci < 32; ++ci) {
        float v = tin[(b * 32 + ci) * 4096 + px];
#pragma unroll
        for (int co = 0; co < 16; ++co)
            acc[co] += v * w[(cg * 16 + co) * 32 + ci];
    }
#pragma unroll
    for (int co = 0; co < 16; ++co) {
        int o = (b * 128 + cg * 16 + co) * 4096 + px;
        xbuf[o] = xbuf[o] + frelu(acc[co]);
    }
}

// ---------- VQ pass 1: direct (z-e)^2, exact reference semantics, 4 e-slices ----
__global__ __launch_bounds__(256) void k_vq1(const float* __restrict__ z,
    const float* __restrict__ emb, float* __restrict__ distb, int* __restrict__ idxb)
{
    const int gid = blockIdx.x * 256 + threadIdx.x;   // 262144
    const int px = gid & 65535, slice = gid >> 16;
    const int b = px >> 12, h = (px >> 6) & 63, wq = px & 63;
    float zr[64];
#pragma unroll
    for (int d = 0; d < 64; ++d)
        zr[d] = z[((b * 64 + d) * 64 + h) * 64 + wq];

    float best = 3.4e38f; int bi = 0;
    const int e0 = slice * 128;
#pragma unroll 1
    for (int e = 0; e < 128; ++e) {
        const float* er = emb + (e0 + e) * 64;        // block-uniform -> s_load
        float dist = 0.f;
#pragma unroll
        for (int d = 0; d < 64; ++d) {
            float df = zr[d] - er[d];
            dist += df * df;                           // single chain, ascending d
        }
        if (dist < best) { best = dist; bi = e0 + e; } // strict < -> first min
    }
    distb[gid] = best;
    idxb[gid] = bi;
}

// ---------- VQ pass 2: merge slices (ascending -> first-min tiebreak), loss part -
__global__ __launch_bounds__(256) void k_vq2(const float* __restrict__ distb,
    const int* __restrict__ idxb, int* __restrict__ idx, float* __restrict__ part)
{
    const int t = threadIdx.x;
    const int px = blockIdx.x * 256 + t;
    float best = distb[px]; int bi = idxb[px];
#pragma unroll
    for (int s2 = 1; s2 < 4; ++s2) {
        float d = distb[s2 * 65536 + px];
        int i2 = idxb[s2 * 65536 + px];
        if (d < best) { best = d; bi = i2; }
    }
    idx[px] = bi;
    float s = best;
#pragma unroll
    for (int off = 32; off > 0; off >>= 1) s += __shfl_down(s, off, 64);
    __shared__ float sw[4];
    if ((t & 63) == 0) sw[t >> 6] = s;
    __syncthreads();
    if (t == 0) part[blockIdx.x] = sw[0] + sw[1] + sw[2] + sw[3];
}

// ---------- build quantized NCHW via LDS transpose ------------------------------
__global__ __launch_bounds__(256) void k_qbuild(const int* __restrict__ idx,
    const float* __restrict__ emb, float* __restrict__ q)
{
    const int t = threadIdx.x;
    const int bh = blockIdx.x;            // b*64 + h
    const int b = bh >> 6, h = bh & 63;
    __shared__ int s_idx[64];
    __shared__ float s_e[64 * 65];
    if (t < 64) s_idx[t] = idx[(b << 12) | (h << 6) | t];
    __syncthreads();
#pragma unroll
    for (int k = 0; k < 16; ++k) {
        int i = t + (k << 8);
        int wq = i >> 6, d = i & 63;
        s_e[wq * 65 + d] = emb[s_idx[wq] * 64 + d];   // coalesced emb rows
    }
    __syncthreads();
#pragma unroll
    for (int k = 0; k < 16; ++k) {
        int i = t + (k << 8);
        int d = i >> 6, wq = i & 63;
        q[((b * 64 + d) * 64 + h) * 64 + wq] = s_e[wq * 65 + d];
    }
}

__global__ __launch_bounds__(256) void k_loss(const float* __restrict__ part,
    float* __restrict__ out)
{
    int t = threadIdx.x;
    float s = part[t];
#pragma unroll
    for (int off = 32; off > 0; off >>= 1) s += __shfl_down(s, off, 64);
    __shared__ float sw[4];
    if ((t & 63) == 0) sw[t >> 6] = s;
    __syncthreads();
    if (t == 0) out[3145728] = 1.25f * (sw[0] + sw[1] + sw[2] + sw[3]) / 4194304.0f;
}

// ---------- ConvTranspose2d k4 s2 p1 + bias + relu, as 4 parity sub-convs -------
template<int CIN, int COUT, int COT, int IW>
__global__ __launch_bounds__(256) void k_convTP(const float* __restrict__ in,
    const float* __restrict__ w, const float* __restrict__ bias, float* __restrict__ out)
{
    constexpr int NTX = IW / 4;           // threads along x
    constexpr int NTY = 256 / NTX;        // rows per tile
    constexpr int NCG = COUT / COT;
    constexpr int STR = IW + 8;           // LDS row stride
    const int t = threadIdx.x;
    const int ty = t / NTX, tx = t % NTX;
    const int rt = blockIdx.x;            // IW/NTY row tiles
    const int bcg = blockIdx.y;
    const int b = bcg / NCG, cg = bcg % NCG;
    const int par = blockIdx.z;
    const int py = par >> 1, px = par & 1;
    const int y0 = rt * NTY;
    const int pr0 = y0 - 1 + py;          // first staged global row
    const int oc0 = cg * COT;

    __shared__ __align__(16) float s_a[8][NTY + 1][STR];

    // col c holds gx = c - 1 + px.  Always-zero halo col: c=0 (px=0) or c=IW (px=1).
    {
        const int zc = px ? IW : 0;
        for (int i = t; i < 8 * (NTY + 1); i += 256)
            s_a[i / (NTY + 1)][i % (NTY + 1)][zc] = 0.f;
    }
    const int csh = 1 - px;               // store col = c + csh for gx = c

    float acc[4][COT];
#pragma unroll
    for (int j = 0; j < 4; ++j)
#pragma unroll
        for (int c = 0; c < COT; ++c) acc[j][c] = 0.f;

    const int kyA = py ? 0 : 1, kyB = py ? 2 : 3;
    const int kxA = px ? 0 : 1, kxB = px ? 2 : 3;

#pragma unroll 1
    for (int cc = 0; cc < CIN / 8; ++cc) {
        __syncthreads();
        for (int ci = 0; ci < 8; ++ci) {
            const float* src = in + (size_t)((b * CIN + cc * 8 + ci) * IW) * IW;
            for (int j = t; j < (NTY + 1) * IW; j += 256) {
                int r = j / IW, c = j % IW;       // IW is pow2 -> shift/mask
                int gy = pr0 + r;
                float v = ((unsigned)gy < (unsigned)IW) ? src[gy * IW + c] : 0.f;
                s_a[ci][r][c + csh] = v;
            }
        }
        __syncthreads();
        for (int ci = 0; ci < 8; ++ci) {
            float p0[5], p1[5];
            {
                const float* r0 = &s_a[ci][ty][4 * tx];
                const float* r1 = &s_a[ci][ty + 1][4 * tx];
                float4 m0 = *reinterpret_cast<const float4*>(r0);
                float4 m1 = *reinterpret_cast<const float4*>(r1);
                p0[0] = m0.x; p0[1] = m0.y; p0[2] = m0.z; p0[3] = m0.w; p0[4] = r0[4];
                p1[0] = m1.x; p1[1] = m1.y; p1[2] = m1.z; p1[3] = m1.w; p1[4] = r1[4];
            }
            const int wbase = ((cc * 8 + ci) * COUT + oc0) * 16;
#pragma unroll
            for (int kyi = 0; kyi < 2; ++kyi) {
                const int ky = kyi ? kyB : kyA;
                const float* pr = kyi ? p0 : p1;
#pragma unroll
                for (int kxi = 0; kxi < 2; ++kxi) {
                    const int kx = kxi ? kxB : kxA;
                    const int cs = 1 - kxi;
#pragma unroll
                    for (int co = 0; co < COT; ++co) {
                        float wv = w[wbase + co * 16 + ky * 4 + kx];
#pragma unroll
                        for (int j = 0; j < 4; ++j)
                            acc[j][co] += pr[j + cs] * wv;
                    }
                }
            }
        }
    }
    const int oy = 2 * (y0 + ty) + py;
#pragma unroll
    for (int co = 0; co < COT; ++co) {
        int oc = oc0 + co;
        float bv = bias[oc];
#pragma unroll
        for (int j = 0; j < 4; ++j) {
            int ox = 8 * tx + 2 * j + px;
            out[((b * COUT + oc) * (2 * IW) + oy) * (2 * IW) + ox] =
                frelu(acc[j][co] + bv);
        }
    }
}

extern "C" void kernel_launch(void* const* d_in, const int* in_sizes, int n_in,
                              void* d_out, int out_size, void* d_ws, size_t ws_size,
                              hipStream_t stream)
{
    (void)in_sizes; (void)n_in; (void)out_size; (void)ws_size;
    const float* x    = (const float*)d_in[0];
    const float* emb  = (const float*)d_in[1];
    const float* ew1  = (const float*)d_in[2];
    const float* eb1  = (const float*)d_in[3];
    const float* ew2  = (const float*)d_in[4];
    const float* eb2  = (const float*)d_in[5];
    const float* er1a = (const float*)d_in[6];
    const float* er1b = (const float*)d_in[7];
    const float* er2a = (const float*)d_in[8];
    const float* er2b = (const float*)d_in[9];
    const float* ew3w = (const float*)d_in[10];
    const float* eb3  = (const float*)d_in[11];
    const float* dw1  = (const float*)d_in[12];
    const float* db1  = (const float*)d_in[13];
    const float* dr1a = (const float*)d_in[14];
    const float* dr1b = (const float*)d_in[15];
    const float* dr2a = (const float*)d_in[16];
    const float* dr2b = (const float*)d_in[17];
    const float* dtw1 = (const float*)d_in[18];
    const float* dtb1 = (const float*)d_in[19];
    const float* dtw2 = (const float*)d_in[20];
    const float* dtb2 = (const float*)d_in[21];
    float* out = (float*)d_out;
    float* ws  = (float*)d_ws;

    float* A    = ws;                          // [16,64,128,128] h1; later convT1 out
    float* Bf   = ws + 16777216;               // [16,128,64,64]
    float* T    = ws;                          // [16,32,64,64]   (h1 dead after ew2)
    float* Z    = ws + 2097152;                // [16,64,64,64]
    float* Q    = ws + 6291456;                // [16,64,64,64]
    int*   IDX  = (int*)(ws + 10485760);       // 65536
    float* PART = ws + 10551296;               // 256
    float* DISTB= ws + 10552064;               // 4*65536
    int*   IDXB = (int*)(ws + 10814208);       // 4*65536

    k_ew1<<<dim3(64, 16), 256, 0, stream>>>(x, ew1, eb1, A);
    k_ew2<<<dim3(4, 128), 256, 0, stream>>>(A, ew2, eb2, Bf);
    k_gconvQ22<128, 32, true, false><<<dim3(4, 64), 256, 0, stream>>>(Bf, er1a, nullptr, T);
    k_res1x1<<<2048, 256, 0, stream>>>(T, er1b, Bf);
    k_gconvQ22<128, 32, true, false><<<dim3(4, 64), 256, 0, stream>>>(Bf, er2a, nullptr, T);
    k_res1x1<<<2048, 256, 0, stream>>>(T, er2b, Bf);
    k_gconvW4<128, 64, 8, false, true><<<dim3(4, 128), 256, 0, stream>>>(Bf, ew3w, eb3, Z);
    k_vq1<<<1024, 256, 0, stream>>>(Z, emb, DISTB, IDXB);
    k_vq2<<<256, 256, 0, stream>>>(DISTB, IDXB, IDX, PART);
    k_loss<<<1, 256, 0, stream>>>(PART, out);
    k_qbuild<<<1024, 256, 0, stream>>>(IDX, emb, Q);
    k_gconvW4<64, 128, 16, false, true><<<dim3(4, 128), 256, 0, stream>>>(Q, dw1, db1, Bf);
    k_gconvQ22<128, 32, true, false><<<dim3(4, 64), 256, 0, stream>>>(Bf, dr1a, nullptr, T);
    k_res1x1<<<2048, 256, 0, stream>>>(T, dr1b, Bf);
    k_gconvQ22<128, 32, true, false><<<dim3(4, 64), 256, 0, stream>>>(Bf, dr2a, nullptr, T);
    k_res1x1<<<2048, 256, 0, stream>>>(T, dr2b, Bf);
    k_convTP<128, 64, 16, 64><<<dim3(4, 64, 4), 256, 0, stream>>>(Bf, dtw1, dtb1, A);
    k_convTP<64, 3, 3, 128><<<dim3(16, 16, 4), 256, 0, stream>>>(A, dtw2, dtb2, out);
}